// Round 5
// baseline (427.942 us; speedup 1.0000x reference)
//
#include <hip/hip_runtime.h>

#define NN 16384          // nodes
#define NE 262144         // edges
#define N64 (NN * 64)

typedef unsigned short u16;
typedef __attribute__((ext_vector_type(8))) short short8;
typedef __attribute__((ext_vector_type(4))) float f32x4;

__device__ __forceinline__ float us2f(u16 u) {
    union { unsigned int i; float f; } v; v.i = ((unsigned int)u) << 16; return v.f;
}
__device__ __forceinline__ u16 f2us(float x) {   // f32 -> bf16 bits, RNE
    union { float f; unsigned int i; } u; u.f = x;
    unsigned int r = u.i + 0x7FFF + ((u.i >> 16) & 1);
    return (u16)(r >> 16);
}
__device__ __forceinline__ float silu_f(float x) { return x / (1.0f + __expf(-x)); }
__device__ __forceinline__ float ldf(const void* p, long i, int f) {
    return f ? ((const float*)p)[i] : us2f(((const u16*)p)[i]);
}

// ---------------- dtype sniff (drives only k_convert) --------------------------
__global__ void k_sniff(const u16* __restrict__ re, int* __restrict__ flag) {
    int t = threadIdx.x;
    int hit = (re[t] >= 0x4000) ? 1 : 0;
    unsigned long long b = __ballot(hit);
    if (t == 0) *flag = (__popcll(b) >= 4) ? 1 : 0;   // 1 => f32 inputs
}

// ---------------- convert all float tensors to bf16 + x1 transpose + hist ------
// Weight tensors consumed as MFMA B-operands are stored TRANSPOSED so the
// consumer kernels can fragment-load them with single short8 vector loads:
//   c_Wup0/c_Wup1 : [k_out=64][m=64]      (orig [m][k])
//   c_Rw2         : [k_out=256][m=64]     (orig [m=64][k=256])
//   c_Wd0         : [n=128][k=128]        (orig [k][n])
//   c_Wd1         : [n=64][k=128]         (orig [k=128][n=64])
//   c_Wsc0        : [s][n=128][m=64]      (orig [s][m=64][n=128])
//   c_Wsc1        : [s][n=64][m=64]       (orig [s][m][n])
#define SB0 1048576L
#define SB1 4194304L
#define SB2 4456448L
#define SB3 5242880L
#define SB4 7340032L
#define SB5 7344128L
#define SB6 7348224L
#define SB7 7348736L
#define SB8 7365120L
#define SB9 7381504L
#define SB10 7389696L
#define SB11 7422464L
#define SB12 7438848L   // total; /256 = 29058 blocks

__global__ void k_convert(const void* x0, const void* x1, const void* ey0, const void* ey1,
                          const void* re, const void* Wup0, const void* Wup1, const void* Rw1,
                          const void* Rw2, const void* Wd0, const void* Wd1, const void* Wsc0,
                          const void* Wsc1, const int* __restrict__ flag,
                          const int* __restrict__ recv, int* __restrict__ cnt,
                          u16* c_x0, u16* x1T, u16* c_ey0, u16* c_ey1, u16* c_re,
                          u16* c_Wup0, u16* c_Wup1, u16* c_Rw1, u16* c_Rw2,
                          u16* c_Wd0, u16* c_Wd1, u16* c_Wsc0, u16* c_Wsc1) {
    long i = (long)blockIdx.x * 256 + threadIdx.x;
    int f = *flag;
    if (i < NE) atomicAdd(&cnt[recv[i]], 1);          // fused histogram
    if (i < SB0)       { c_x0[i]          = f2us(ldf(x0, i, f)); }
    else if (i < SB1)  {
        long j = i - SB0;
        int n = (int)(j / 192); int r = (int)(j % 192); int m = r / 3; int c = r % 3;
        x1T[(long)c * N64 + (long)n * 64 + m] = f2us(ldf(x1, j, f));
    }
    else if (i < SB2)  { c_ey0[i - SB1]   = f2us(ldf(ey0, i - SB1, f)); }
    else if (i < SB3)  { c_ey1[i - SB2]   = f2us(ldf(ey1, i - SB2, f)); }
    else if (i < SB4)  { c_re[i - SB3]    = f2us(ldf(re, i - SB3, f)); }
    else if (i < SB5)  { long j = i - SB4;  long r = j >> 6, c = j & 63;
                         c_Wup0[c * 64 + r]  = f2us(ldf(Wup0, j, f)); }
    else if (i < SB6)  { long j = i - SB5;  long r = j >> 6, c = j & 63;
                         c_Wup1[c * 64 + r]  = f2us(ldf(Wup1, j, f)); }
    else if (i < SB7)  { c_Rw1[i - SB6]   = f2us(ldf(Rw1, i - SB6, f)); }
    else if (i < SB8)  { long j = i - SB7;  long r = j >> 8, c = j & 255;
                         c_Rw2[c * 64 + r]   = f2us(ldf(Rw2, j, f)); }
    else if (i < SB9)  { long j = i - SB8;  long r = j >> 7, c = j & 127;
                         c_Wd0[c * 128 + r]  = f2us(ldf(Wd0, j, f)); }
    else if (i < SB10) { long j = i - SB9;  long r = j >> 6, c = j & 63;
                         c_Wd1[c * 128 + r]  = f2us(ldf(Wd1, j, f)); }
    else if (i < SB11) { long j = i - SB10; long s = j >> 13, rm = j & 8191;
                         long r = rm >> 7, c = rm & 127;
                         c_Wsc0[s * 8192 + c * 64 + r] = f2us(ldf(Wsc0, j, f)); }
    else               { long j = i - SB11; long s = j >> 12, rm = j & 4095;
                         long r = rm >> 6, c = rm & 63;
                         c_Wsc1[s * 4096 + c * 64 + r] = f2us(ldf(Wsc1, j, f)); }
}

// ---------------- CSR scan + scatter -------------------------------------------
__global__ void k_scan(const int* __restrict__ cnt, int* __restrict__ offs,
                       int* __restrict__ cursor) {
    __shared__ int sd[256];
    int t = threadIdx.x;
    int base = t * 64;
    const int4* c4 = (const int4*)cnt;
    int loc[64];
#pragma unroll
    for (int i = 0; i < 16; i++) {
        int4 v = c4[t * 16 + i];
        loc[i * 4 + 0] = v.x; loc[i * 4 + 1] = v.y; loc[i * 4 + 2] = v.z; loc[i * 4 + 3] = v.w;
    }
    int sum = 0;
#pragma unroll
    for (int i = 0; i < 64; i++) sum += loc[i];
    sd[t] = sum; __syncthreads();
    for (int off = 1; off < 256; off <<= 1) {
        int v = (t >= off) ? sd[t - off] : 0;
        __syncthreads();
        sd[t] += v;
        __syncthreads();
    }
    int run = sd[t] - sum;
    for (int i = 0; i < 64; i++) {
        offs[base + i] = run; cursor[base + i] = run;
        run += loc[i];
    }
    if (t == 255) offs[NN] = run;
}

// meta.w packs edge id (18 bits) | receiver node (14 bits) -------------------
__global__ void k_scatter(const int* __restrict__ recv, const int* __restrict__ senders,
                          const u16* __restrict__ ey0, const u16* __restrict__ ey1,
                          int* __restrict__ cursor, int4* __restrict__ meta) {
    int e = blockIdx.x * 256 + threadIdx.x;
    int node = recv[e];
    int p = atomicAdd(&cursor[node], 1);
    unsigned y0  = ey0[e];
    unsigned y1x = ey1[(long)e * 3 + 0];
    unsigned y1y = ey1[(long)e * 3 + 1];
    unsigned y1z = ey1[(long)e * 3 + 2];
    int4 m;
    m.x = senders[e];
    m.y = (int)(y0 | (y1x << 16));
    m.z = (int)(y1y | (y1z << 16));
    m.w = (int)((unsigned)e | ((unsigned)node << 18));
    meta[p] = m;
}

// ---------------- linear_up: h[node][64ch][4comp] interleaved bf16 --------------
__global__ void k_up_gemm(const u16* __restrict__ x0, const u16* __restrict__ x1T,
                          const u16* __restrict__ Wup0, const u16* __restrict__ Wup1,
                          u16* __restrict__ h) {
    int inst = blockIdx.y;
    int wv = threadIdx.x >> 6, lane = threadIdx.x & 63;
    int lhi = lane >> 4, llo = lane & 15;
    int mb = blockIdx.x * 256 + wv * 64;
    const u16* B = (inst == 0) ? Wup0 : Wup1;     // transposed [k_out=64][m=64]
    const u16* A = (inst == 0) ? x0 : (x1T + (long)(inst - 1) * N64);

    short8 bfr[4][2];
#pragma unroll
    for (int t = 0; t < 4; t++)
#pragma unroll
        for (int s = 0; s < 2; s++)
            bfr[t][s] = *reinterpret_cast<const short8*>(B + (long)(t * 16 + llo) * 64 + s * 32 + lhi * 8);

    f32x4 acc[4][4];
#pragma unroll
    for (int i = 0; i < 4; i++)
#pragma unroll
        for (int t = 0; t < 4; t++) acc[i][t] = 0.0f;

#pragma unroll
    for (int s = 0; s < 2; s++) {
        short8 af[4];
#pragma unroll
        for (int i = 0; i < 4; i++)
            af[i] = *reinterpret_cast<const short8*>(A + (long)(mb + i * 16 + llo) * 64 + s * 32 + lhi * 8);
#pragma unroll
        for (int i = 0; i < 4; i++)
#pragma unroll
            for (int t = 0; t < 4; t++)
                acc[i][t] = __builtin_amdgcn_mfma_f32_16x16x32_bf16(af[i], bfr[t][s], acc[i][t], 0, 0, 0);
    }
#pragma unroll
    for (int i = 0; i < 4; i++)
#pragma unroll
        for (int t = 0; t < 4; t++)
#pragma unroll
            for (int r = 0; r < 4; r++)
                h[(long)(mb + i * 16 + lhi * 4 + r) * 256 + (t * 16 + llo) * 4 + inst] =
                    f2us(acc[i][t][r] * 0.125f);
}

// ---------------- fused radial MLP + tensor-product gather (node-aligned) -------
// One block = EN whole nodes -> every node's CSR run lies inside one block:
// NO atomics, NO abuf memset, plain bf16 row stores.
// The block's edge range [s0,s1) is processed in 64-slot tiles:
//   phase A: radial hidden MLP for the tile's slots (edge id from meta, masked
//            to 18 bits so padded slots still read in-bounds);
//   phase B: 64x256 MFMA -> per-slot weights in w_lds (round-3 verbatim);
//   phase C: round-robin node->wave walk (node i -> wave i&3) so each tile's
//            ~4 node-runs land on distinct waves; lane = channel; acc in regs
//            persists across tiles; flush = coalesced bf16 store.
#define EN 16
#define RROW 276
__global__ void __launch_bounds__(256, 3)
k_edge(const u16* __restrict__ re, const u16* __restrict__ Rw1,
       const u16* __restrict__ Rw2, const int4* __restrict__ meta,
       const u16* __restrict__ h, const int* __restrict__ offs,
       u16* __restrict__ abuf) {
    __shared__ u16 hid_s[64][72];
    __shared__ u16 w_lds[64 * RROW];
    __shared__ int offs_s[EN + 1];
    int tid = threadIdx.x;
    int wv = tid >> 6, lane = tid & 63, lhi = lane >> 4, llo = lane & 15;
    int n0 = blockIdx.x * EN;
    if (tid <= EN) offs_s[tid] = offs[n0 + tid];
    __syncthreads();
    int s0 = offs_s[0], s1 = offs_s[EN];
    int T = (s1 - s0 + 63) >> 6;

    const float qn = 0.25f;                 // 1/sqrt(avg_neigh)
    const float rs3 = 0.57735026918962576f; // 1/sqrt(3)
    int ni = wv;                            // this wave's next node (round-robin)
    float acc[8];
#pragma unroll
    for (int r = 0; r < 8; r++) acc[r] = 0.f;

    for (int t = 0; t < T; t++) {
        int ts = s0 + t * 64;
        // ---- phase A: radial hidden layer for slots [ts, ts+64) --------------
        {
            int el = tid >> 2;
            int jb = (tid & 3) * 16;
            int e = ((const int*)meta)[(long)(ts + el) * 4 + 3] & 0x3FFFF; // always < NE
            short8 r8 = *reinterpret_cast<const short8*>(re + (long)e * 8);
            float rr[8];
#pragma unroll
            for (int r = 0; r < 8; r++) rr[r] = us2f((u16)r8[r]);
            float hv[16];
#pragma unroll
            for (int q = 0; q < 2; q++) {
                short8 w8 = *reinterpret_cast<const short8*>(Rw1 + jb + q * 8);
#pragma unroll
                for (int j = 0; j < 8; j++) hv[q * 8 + j] = rr[0] * us2f((u16)w8[j]);
            }
#pragma unroll
            for (int r = 1; r < 8; r++) {
#pragma unroll
                for (int q = 0; q < 2; q++) {
                    short8 w8 = *reinterpret_cast<const short8*>(Rw1 + (long)r * 64 + jb + q * 8);
#pragma unroll
                    for (int j = 0; j < 8; j++) hv[q * 8 + j] += rr[r] * us2f((u16)w8[j]);
                }
            }
#pragma unroll
            for (int q = 0; q < 4; q++) {
                ushort4 pk;
                pk.x = f2us(silu_f(hv[q * 4 + 0] * 0.35355339059327373f));
                pk.y = f2us(silu_f(hv[q * 4 + 1] * 0.35355339059327373f));
                pk.z = f2us(silu_f(hv[q * 4 + 2] * 0.35355339059327373f));
                pk.w = f2us(silu_f(hv[q * 4 + 3] * 0.35355339059327373f));
                *reinterpret_cast<ushort4*>(&hid_s[el][jb + q * 4]) = pk;
            }
        }
        __syncthreads();

        // ---- phase B: hid[64x64] @ Rw2T -> w_lds[64 slots][256] ---------------
        {
            short8 bfr[4][2];
#pragma unroll
            for (int tt = 0; tt < 4; tt++)
#pragma unroll
                for (int s = 0; s < 2; s++)
                    bfr[tt][s] = *reinterpret_cast<const short8*>(
                        Rw2 + (long)(wv * 64 + tt * 16 + llo) * 64 + s * 32 + lhi * 8);
            f32x4 ac[4][4];
#pragma unroll
            for (int i = 0; i < 4; i++)
#pragma unroll
                for (int tt = 0; tt < 4; tt++) ac[i][tt] = 0.0f;
#pragma unroll
            for (int s = 0; s < 2; s++) {
                short8 af[4];
#pragma unroll
                for (int i = 0; i < 4; i++)
                    af[i] = *reinterpret_cast<const short8*>(&hid_s[i * 16 + llo][s * 32 + lhi * 8]);
#pragma unroll
                for (int i = 0; i < 4; i++)
#pragma unroll
                    for (int tt = 0; tt < 4; tt++)
                        ac[i][tt] = __builtin_amdgcn_mfma_f32_16x16x32_bf16(af[i], bfr[tt][s], ac[i][tt], 0, 0, 0);
            }
#pragma unroll
            for (int i = 0; i < 4; i++)
#pragma unroll
                for (int tt = 0; tt < 4; tt++)
#pragma unroll
                    for (int r = 0; r < 4; r++)
                        w_lds[(i * 16 + lhi * 4 + r) * RROW + wv * 64 + tt * 16 + llo] =
                            f2us(ac[i][tt][r] * 0.125f);
        }
        __syncthreads();

        // ---- phase C: this wave's node-runs intersecting [ts, ts+64) ----------
        {
            int te = ts + 64;
            while (ni < EN) {
                int rs = offs_s[ni], ren = offs_s[ni + 1];
                if (rs >= te) break;                 // starts in a later tile
                int a = rs > ts ? rs : ts;
                int b = ren < te ? ren : te;
                if (a < b) {
                    int4 m = meta[a];
                    ushort4 hv = *reinterpret_cast<const ushort4*>(h + (long)m.x * 256 + lane * 4);
                    for (int p = a; p < b; p++) {
                        int4 mn = m; ushort4 hn = hv;
                        if (p + 1 < b) {
                            mn = meta[p + 1];
                            hn = *reinterpret_cast<const ushort4*>(h + (long)mn.x * 256 + lane * 4);
                        }
                        int sl = p - ts;
                        float w0 = us2f(w_lds[sl * RROW + lane]);
                        float w1 = us2f(w_lds[sl * RROW + 64 + lane]);
                        float w2 = us2f(w_lds[sl * RROW + 128 + lane]);
                        float w3 = us2f(w_lds[sl * RROW + 192 + lane]);
                        float y0  = us2f((u16)((unsigned)m.y & 0xffff));
                        float y1x = us2f((u16)((unsigned)m.y >> 16));
                        float y1y = us2f((u16)((unsigned)m.z & 0xffff));
                        float y1z = us2f((u16)((unsigned)m.z >> 16));
                        float sv0 = us2f(hv.x), s1x = us2f(hv.y), s1y = us2f(hv.z), s1z = us2f(hv.w);
                        acc[0] += w0 * sv0 * y0;
                        acc[1] += w1 * (s1x * y1x + s1y * y1y + s1z * y1z);
                        acc[2] += w2 * sv0 * y1x;  acc[3] += w3 * s1x * y0;
                        acc[4] += w2 * sv0 * y1y;  acc[5] += w3 * s1y * y0;
                        acc[6] += w2 * sv0 * y1z;  acc[7] += w3 * s1z * y0;
                        m = mn; hv = hn;
                    }
                }
                if (ren <= te) {                     // run complete -> plain store
                    u16* ab = abuf + (long)(n0 + ni) * 512 + lane;
                    ab[0]   = f2us(acc[0] * qn);
                    ab[64]  = f2us(acc[1] * qn * rs3);
                    ab[128] = f2us(acc[2] * qn);
                    ab[192] = f2us(acc[3] * qn);
                    ab[256] = f2us(acc[4] * qn);
                    ab[320] = f2us(acc[5] * qn);
                    ab[384] = f2us(acc[6] * qn);
                    ab[448] = f2us(acc[7] * qn);
#pragma unroll
                    for (int r = 0; r < 8; r++) acc[r] = 0.f;
                    ni += 4;
                } else break;                        // continues into next tile
            }
        }
        __syncthreads();
    }
    // trailing degree-0 nodes (runs at exactly s1 when s1 == s0 + 64*T, or T==0)
    while (ni < EN) {
        u16* ab = abuf + (long)(n0 + ni) * 512 + lane;
        u16 z = f2us(0.f);
        ab[0] = z; ab[64] = z; ab[128] = z; ab[192] = z;
        ab[256] = z; ab[320] = z; ab[384] = z; ab[448] = z;
        ni += 4;
    }
}

// ---------------- linear_down + species sc + gate (MFMA) ------------------------
// Block = 32 nodes, 5 waves: wave g = output group {scal, gate, vx, vy, vz}.
// Vector outputs staged in LDS and written as fully-coalesced float4.
#define DN 32
__global__ void __launch_bounds__(320, 3)
k_down(const u16* __restrict__ abuf, const u16* __restrict__ x0,
       const u16* __restrict__ x1T, const int* __restrict__ species,
       const u16* __restrict__ Wd0T, const u16* __restrict__ Wd1T,
       const u16* __restrict__ Wsc0T, const u16* __restrict__ Wsc1T,
       float* __restrict__ out) {
    __shared__ float gate_s[DN][65];
    __shared__ float vec_s[DN * 192];       // raw f1 in output order [row][col*3+c]
    __shared__ int sp_s[DN];
    int tid = threadIdx.x;
    int g = tid >> 6;
    int lane = tid & 63, lhi = lane >> 4, llo = lane & 15;
    int node0 = blockIdx.x * DN;
    if (tid < DN) sp_s[tid] = species[node0 + tid];
    __syncthreads();

    const u16* Ad; const u16* BdT; int bcol;
    const u16* As; const u16* BsT; int sstr;
    if (g <= 1) { Ad = abuf; BdT = Wd0T; bcol = g * 64; As = x0; BsT = Wsc0T; sstr = 8192; }
    else        { Ad = abuf + (g - 1) * 128; BdT = Wd1T; bcol = 0;
                  As = x1T + (long)(g - 2) * N64; BsT = Wsc1T; sstr = 4096; }

    const float inv2 = 0.08838834764831845f;  // 1/sqrt(128)
    const float inv  = 0.125f;                // 1/sqrt(64)

    // ---- self-connection phase: all species, row-select -----------------------
    short8 a2[DN / 16][2];
#pragma unroll
    for (int rt = 0; rt < DN / 16; rt++)
#pragma unroll
        for (int ks = 0; ks < 2; ks++)
            a2[rt][ks] = *reinterpret_cast<const short8*>(
                As + (long)(node0 + rt * 16 + llo) * 64 + ks * 32 + lhi * 8);

    f32x4 res[DN / 16][4];
#pragma unroll
    for (int rt = 0; rt < DN / 16; rt++)
#pragma unroll
        for (int ct = 0; ct < 4; ct++) res[rt][ct] = 0.0f;

    for (int s = 0; s < 4; s++) {
        short8 bs[4][2];
#pragma unroll
        for (int ct = 0; ct < 4; ct++)
#pragma unroll
            for (int ks = 0; ks < 2; ks++)
                bs[ct][ks] = *reinterpret_cast<const short8*>(
                    BsT + (long)s * sstr + (long)(bcol + ct * 16 + llo) * 64 + ks * 32 + lhi * 8);
#pragma unroll
        for (int rt = 0; rt < DN / 16; rt++) {
            f32x4 accs[4];
#pragma unroll
            for (int ct = 0; ct < 4; ct++) accs[ct] = 0.0f;
#pragma unroll
            for (int ks = 0; ks < 2; ks++)
#pragma unroll
                for (int ct = 0; ct < 4; ct++)
                    accs[ct] = __builtin_amdgcn_mfma_f32_16x16x32_bf16(a2[rt][ks], bs[ct][ks], accs[ct], 0, 0, 0);
#pragma unroll
            for (int r = 0; r < 4; r++) {
                int sp = sp_s[rt * 16 + lhi * 4 + r];
                if (sp == s)
#pragma unroll
                    for (int ct = 0; ct < 4; ct++) res[rt][ct][r] = accs[ct][r];
            }
        }
    }

    // ---- linear_down phase -----------------------------------------------------
    short8 bd[4][4];
#pragma unroll
    for (int ct = 0; ct < 4; ct++)
#pragma unroll
        for (int ks = 0; ks < 4; ks++)
            bd[ct][ks] = *reinterpret_cast<const short8*>(
                BdT + (long)(bcol + ct * 16 + llo) * 128 + ks * 32 + lhi * 8);

#pragma unroll
    for (int rt = 0; rt < DN / 16; rt++) {
        f32x4 accd[4];
#pragma unroll
        for (int ct = 0; ct < 4; ct++) accd[ct] = 0.0f;
#pragma unroll
        for (int ks = 0; ks < 4; ks++) {
            short8 a = *reinterpret_cast<const short8*>(
                Ad + (long)(node0 + rt * 16 + llo) * 512 + ks * 32 + lhi * 8);
#pragma unroll
            for (int ct = 0; ct < 4; ct++)
                accd[ct] = __builtin_amdgcn_mfma_f32_16x16x32_bf16(a, bd[ct][ks], accd[ct], 0, 0, 0);
        }
#pragma unroll
        for (int ct = 0; ct < 4; ct++)
#pragma unroll
            for (int r = 0; r < 4; r++) {
                float fvv = 0.5f * (accd[ct][r] * inv2 + res[rt][ct][r] * inv);
                int row = rt * 16 + lhi * 4 + r;
                int col = ct * 16 + llo;
                if (g == 0) {
                    out[(long)(node0 + row) * 64 + col] = silu_f(fvv);
                } else if (g == 1) {
                    gate_s[row][col] = silu_f(fvv);
                } else {
                    vec_s[row * 192 + col * 3 + (g - 2)] = fvv;
                }
            }
    }
    __syncthreads();

    // ---- cooperative coalesced vector store (gate applied here) ---------------
    {
        float* vout = out + (long)N64 + (long)node0 * 192;
        for (int q4 = tid; q4 < DN * 48; q4 += 320) {
            int q = q4 * 4;
            int row = q4 / 48;                // 48 float4 per node row
            int rem = q - row * 192;
            f32x4 v = *reinterpret_cast<const f32x4*>(&vec_s[q]);
#pragma unroll
            for (int e = 0; e < 4; e++) v[e] *= gate_s[row][(rem + e) / 3];
            *reinterpret_cast<f32x4*>(vout + q) = v;
        }
    }
}

// ---------------- host launch --------------------------------------------------
extern "C" void kernel_launch(void* const* d_in, const int* in_sizes, int n_in,
                              void* d_out, int out_size, void* d_ws, size_t ws_size,
                              hipStream_t stream) {
    const int* senders   = (const int*)d_in[5];
    const int* receivers = (const int*)d_in[6];
    const int* species   = (const int*)d_in[7];
    float* out = (float*)d_out;

    char* ws = (char*)d_ws;
    size_t o = 0;
    auto alloc = [&](size_t bytes) { size_t p = o; o = (o + bytes + 255) & ~255UL; return p; };
    int* flag   = (int*)(ws + alloc(4));
    int* cnt    = (int*)(ws + alloc((size_t)NN * 4));
    int* offs   = (int*)(ws + alloc((size_t)(NN + 1) * 4));
    int* cursor = (int*)(ws + alloc((size_t)NN * 4));
    int4* meta  = (int4*)(ws + alloc((size_t)(NE + 64) * 16));   // +64 pad slots
    u16* c_x0   = (u16*)(ws + alloc(SB0 * 2));
    u16* x1T    = (u16*)(ws + alloc((size_t)3 * N64 * 2));
    u16* c_ey0  = (u16*)(ws + alloc((SB2 - SB1) * 2));
    u16* c_ey1  = (u16*)(ws + alloc((SB3 - SB2) * 2));
    u16* c_re   = (u16*)(ws + alloc((SB4 - SB3) * 2));
    u16* c_Wup0 = (u16*)(ws + alloc((SB5 - SB4) * 2));
    u16* c_Wup1 = (u16*)(ws + alloc((SB6 - SB5) * 2));
    u16* c_Rw1  = (u16*)(ws + alloc((SB7 - SB6) * 2));
    u16* c_Rw2  = (u16*)(ws + alloc((SB8 - SB7) * 2));
    u16* c_Wd0  = (u16*)(ws + alloc((SB9 - SB8) * 2));
    u16* c_Wd1  = (u16*)(ws + alloc((SB10 - SB9) * 2));
    u16* c_Wsc0 = (u16*)(ws + alloc((SB11 - SB10) * 2));
    u16* c_Wsc1 = (u16*)(ws + alloc((SB12 - SB11) * 2));
    u16* h      = (u16*)(ws + alloc((size_t)NN * 256 * 2));   // [node][64][4]
    u16* abuf   = (u16*)(ws + alloc((size_t)NN * 512 * 2));   // [node][512] bf16

    k_sniff<<<1, 64, 0, stream>>>((const u16*)d_in[4], flag);
    (void)hipMemsetAsync(cnt, 0, (size_t)NN * 4, stream);
    k_convert<<<29058, 256, 0, stream>>>(d_in[0], d_in[1], d_in[2], d_in[3], d_in[4],
        d_in[8], d_in[9], d_in[10], d_in[11], d_in[12], d_in[13], d_in[14], d_in[15],
        flag, receivers, cnt,
        c_x0, x1T, c_ey0, c_ey1, c_re,
        c_Wup0, c_Wup1, c_Rw1, c_Rw2, c_Wd0, c_Wd1, c_Wsc0, c_Wsc1);
    k_scan<<<1, 256, 0, stream>>>(cnt, offs, cursor);
    k_scatter<<<NE / 256, 256, 0, stream>>>(receivers, senders, c_ey0, c_ey1,
                                            cursor, meta);

    k_up_gemm<<<dim3(NN / 256, 4), 256, 0, stream>>>(c_x0, x1T, c_Wup0, c_Wup1, h);

    k_edge<<<NN / EN, 256, 0, stream>>>(c_re, c_Rw1, c_Rw2, meta, h, offs, abuf);

    k_down<<<NN / DN, 320, 0, stream>>>(abuf, c_x0, x1T, species,
                                        c_Wd0, c_Wd1, c_Wsc0, c_Wsc1, out);
}

// Round 6
// 269.574 us; speedup vs baseline: 1.5875x; 1.5875x over previous
//
#include <hip/hip_runtime.h>

#define NN 16384          // nodes
#define NE 262144         // edges
#define N64 (NN * 64)

typedef unsigned short u16;
typedef __attribute__((ext_vector_type(8))) short short8;
typedef __attribute__((ext_vector_type(4))) float f32x4;

__device__ __forceinline__ float us2f(u16 u) {
    union { unsigned int i; float f; } v; v.i = ((unsigned int)u) << 16; return v.f;
}
__device__ __forceinline__ u16 f2us(float x) {   // f32 -> bf16 bits, RNE
    union { float f; unsigned int i; } u; u.f = x;
    unsigned int r = u.i + 0x7FFF + ((u.i >> 16) & 1);
    return (u16)(r >> 16);
}
__device__ __forceinline__ float silu_f(float x) { return x / (1.0f + __expf(-x)); }
__device__ __forceinline__ float ldf(const void* p, long i, int f) {
    return f ? ((const float*)p)[i] : us2f(((const u16*)p)[i]);
}
__device__ __forceinline__ short8 f32x8_to_bf16(const float* p) {
    f32x4 a = *reinterpret_cast<const f32x4*>(p);
    f32x4 b = *reinterpret_cast<const f32x4*>(p + 4);
    short8 r;
    r[0] = (short)f2us(a[0]); r[1] = (short)f2us(a[1]);
    r[2] = (short)f2us(a[2]); r[3] = (short)f2us(a[3]);
    r[4] = (short)f2us(b[0]); r[5] = (short)f2us(b[1]);
    r[6] = (short)f2us(b[2]); r[7] = (short)f2us(b[3]);
    return r;
}

// ---------------- dtype sniff (drives only k_convert) --------------------------
__global__ void k_sniff(const u16* __restrict__ re, int* __restrict__ flag) {
    int t = threadIdx.x;
    int hit = (re[t] >= 0x4000) ? 1 : 0;
    unsigned long long b = __ballot(hit);
    if (t == 0) *flag = (__popcll(b) >= 4) ? 1 : 0;   // 1 => f32 inputs
}

// ---------------- convert all float tensors to bf16 + x1 transpose + hist ------
// Weight tensors consumed as MFMA B-operands are stored TRANSPOSED so the
// consumer kernels can fragment-load them with single short8 vector loads:
//   c_Wup0/c_Wup1 : [k_out=64][m=64]      (orig [m][k])
//   c_Rw2         : [k_out=256][m=64]     (orig [m=64][k=256])
//   c_Wd0         : [n=128][k=128]        (orig [k][n])
//   c_Wd1         : [n=64][k=128]         (orig [k=128][n=64])
//   c_Wsc0        : [s][n=128][m=64]      (orig [s][m=64][n=128])
//   c_Wsc1        : [s][n=64][m=64]       (orig [s][m][n])
#define SB0 1048576L
#define SB1 4194304L
#define SB2 4456448L
#define SB3 5242880L
#define SB4 7340032L
#define SB5 7344128L
#define SB6 7348224L
#define SB7 7348736L
#define SB8 7365120L
#define SB9 7381504L
#define SB10 7389696L
#define SB11 7422464L
#define SB12 7438848L   // total; /256 = 29058 blocks

__global__ void k_convert(const void* x0, const void* x1, const void* ey0, const void* ey1,
                          const void* re, const void* Wup0, const void* Wup1, const void* Rw1,
                          const void* Rw2, const void* Wd0, const void* Wd1, const void* Wsc0,
                          const void* Wsc1, const int* __restrict__ flag,
                          const int* __restrict__ recv, int* __restrict__ cnt,
                          u16* c_x0, u16* x1T, u16* c_ey0, u16* c_ey1, u16* c_re,
                          u16* c_Wup0, u16* c_Wup1, u16* c_Rw1, u16* c_Rw2,
                          u16* c_Wd0, u16* c_Wd1, u16* c_Wsc0, u16* c_Wsc1) {
    long i = (long)blockIdx.x * 256 + threadIdx.x;
    int f = *flag;
    if (i < NE) atomicAdd(&cnt[recv[i]], 1);          // fused histogram
    if (i < SB0)       { c_x0[i]          = f2us(ldf(x0, i, f)); }
    else if (i < SB1)  {
        long j = i - SB0;
        int n = (int)(j / 192); int r = (int)(j % 192); int m = r / 3; int c = r % 3;
        x1T[(long)c * N64 + (long)n * 64 + m] = f2us(ldf(x1, j, f));
    }
    else if (i < SB2)  { c_ey0[i - SB1]   = f2us(ldf(ey0, i - SB1, f)); }
    else if (i < SB3)  { c_ey1[i - SB2]   = f2us(ldf(ey1, i - SB2, f)); }
    else if (i < SB4)  { c_re[i - SB3]    = f2us(ldf(re, i - SB3, f)); }
    else if (i < SB5)  { long j = i - SB4;  long r = j >> 6, c = j & 63;
                         c_Wup0[c * 64 + r]  = f2us(ldf(Wup0, j, f)); }
    else if (i < SB6)  { long j = i - SB5;  long r = j >> 6, c = j & 63;
                         c_Wup1[c * 64 + r]  = f2us(ldf(Wup1, j, f)); }
    else if (i < SB7)  { c_Rw1[i - SB6]   = f2us(ldf(Rw1, i - SB6, f)); }
    else if (i < SB8)  { long j = i - SB7;  long r = j >> 8, c = j & 255;
                         c_Rw2[c * 64 + r]   = f2us(ldf(Rw2, j, f)); }
    else if (i < SB9)  { long j = i - SB8;  long r = j >> 7, c = j & 127;
                         c_Wd0[c * 128 + r]  = f2us(ldf(Wd0, j, f)); }
    else if (i < SB10) { long j = i - SB9;  long r = j >> 6, c = j & 63;
                         c_Wd1[c * 128 + r]  = f2us(ldf(Wd1, j, f)); }
    else if (i < SB11) { long j = i - SB10; long s = j >> 13, rm = j & 8191;
                         long r = rm >> 7, c = rm & 127;
                         c_Wsc0[s * 8192 + c * 64 + r] = f2us(ldf(Wsc0, j, f)); }
    else               { long j = i - SB11; long s = j >> 12, rm = j & 4095;
                         long r = rm >> 6, c = rm & 63;
                         c_Wsc1[s * 4096 + c * 64 + r] = f2us(ldf(Wsc1, j, f)); }
}

// ---------------- CSR scan + scatter -------------------------------------------
__global__ void k_scan(const int* __restrict__ cnt, int* __restrict__ offs,
                       int* __restrict__ cursor) {
    __shared__ int sd[256];
    int t = threadIdx.x;
    int base = t * 64;
    const int4* c4 = (const int4*)cnt;
    int loc[64];
#pragma unroll
    for (int i = 0; i < 16; i++) {
        int4 v = c4[t * 16 + i];
        loc[i * 4 + 0] = v.x; loc[i * 4 + 1] = v.y; loc[i * 4 + 2] = v.z; loc[i * 4 + 3] = v.w;
    }
    int sum = 0;
#pragma unroll
    for (int i = 0; i < 64; i++) sum += loc[i];
    sd[t] = sum; __syncthreads();
    for (int off = 1; off < 256; off <<= 1) {
        int v = (t >= off) ? sd[t - off] : 0;
        __syncthreads();
        sd[t] += v;
        __syncthreads();
    }
    int run = sd[t] - sum;
    for (int i = 0; i < 64; i++) {
        offs[base + i] = run; cursor[base + i] = run;
        run += loc[i];
    }
    if (t == 255) offs[NN] = run;
}

// meta.w packs edge id (18 bits) | receiver node (14 bits) -------------------
__global__ void k_scatter(const int* __restrict__ recv, const int* __restrict__ senders,
                          const u16* __restrict__ ey0, const u16* __restrict__ ey1,
                          int* __restrict__ cursor, int4* __restrict__ meta) {
    int e = blockIdx.x * 256 + threadIdx.x;
    int node = recv[e];
    int p = atomicAdd(&cursor[node], 1);
    unsigned y0  = ey0[e];
    unsigned y1x = ey1[(long)e * 3 + 0];
    unsigned y1y = ey1[(long)e * 3 + 1];
    unsigned y1z = ey1[(long)e * 3 + 2];
    int4 m;
    m.x = senders[e];
    m.y = (int)(y0 | (y1x << 16));
    m.z = (int)(y1y | (y1z << 16));
    m.w = (int)((unsigned)e | ((unsigned)node << 18));
    meta[p] = m;
}

// ---------------- linear_up: h[node][64ch][4comp] interleaved bf16 --------------
__global__ void k_up_gemm(const u16* __restrict__ x0, const u16* __restrict__ x1T,
                          const u16* __restrict__ Wup0, const u16* __restrict__ Wup1,
                          u16* __restrict__ h) {
    int inst = blockIdx.y;
    int wv = threadIdx.x >> 6, lane = threadIdx.x & 63;
    int lhi = lane >> 4, llo = lane & 15;
    int mb = blockIdx.x * 256 + wv * 64;
    const u16* B = (inst == 0) ? Wup0 : Wup1;     // transposed [k_out=64][m=64]
    const u16* A = (inst == 0) ? x0 : (x1T + (long)(inst - 1) * N64);

    short8 bfr[4][2];
#pragma unroll
    for (int t = 0; t < 4; t++)
#pragma unroll
        for (int s = 0; s < 2; s++)
            bfr[t][s] = *reinterpret_cast<const short8*>(B + (long)(t * 16 + llo) * 64 + s * 32 + lhi * 8);

    f32x4 acc[4][4];
#pragma unroll
    for (int i = 0; i < 4; i++)
#pragma unroll
        for (int t = 0; t < 4; t++) acc[i][t] = 0.0f;

#pragma unroll
    for (int s = 0; s < 2; s++) {
        short8 af[4];
#pragma unroll
        for (int i = 0; i < 4; i++)
            af[i] = *reinterpret_cast<const short8*>(A + (long)(mb + i * 16 + llo) * 64 + s * 32 + lhi * 8);
#pragma unroll
        for (int i = 0; i < 4; i++)
#pragma unroll
            for (int t = 0; t < 4; t++)
                acc[i][t] = __builtin_amdgcn_mfma_f32_16x16x32_bf16(af[i], bfr[t][s], acc[i][t], 0, 0, 0);
    }
#pragma unroll
    for (int i = 0; i < 4; i++)
#pragma unroll
        for (int t = 0; t < 4; t++)
#pragma unroll
            for (int r = 0; r < 4; r++)
                h[(long)(mb + i * 16 + lhi * 4 + r) * 256 + (t * 16 + llo) * 4 + inst] =
                    f2us(acc[i][t][r] * 0.125f);
}

// ---------------- fused radial MLP + tensor-product gather (CSR-ordered) --------
// One block = 64 consecutive CSR slots. Round-3 structure (verified 276 µs)
// with two surgical changes:
//   (1) hid_s aliased into w_lds (extra barrier inside phase B) -> LDS 34304 B
//       -> 4 blocks/CU (was 3).
//   (2) phase-C gather prefetch deepened to 2 slots ahead.
// Flush stays round-3's simple global f32 atomicAdd per node-run.
#define RROW 268
__global__ void __launch_bounds__(256, 4)
k_edge(const u16* __restrict__ re, const u16* __restrict__ Rw1,
       const u16* __restrict__ Rw2, const int4* __restrict__ meta,
       const u16* __restrict__ h, float* __restrict__ abuf32) {
    __shared__ u16 w_lds[64 * RROW];          // 34304 B; hid aliased below
    u16 (*hid_s)[72] = reinterpret_cast<u16 (*)[72]>(w_lds);

    int tid = threadIdx.x;
    int wv = tid >> 6, lane = tid & 63, lhi = lane >> 4, llo = lane & 15;
    int p0 = blockIdx.x * 64;

    // ---- phase A: radial hidden layer for this block's 64 CSR slots ----------
    {
        int el = tid >> 2;
        int jb = (tid & 3) * 16;
        int e = ((const int*)meta)[(long)(p0 + el) * 4 + 3] & 0x3FFFF;
        short8 r8 = *reinterpret_cast<const short8*>(re + (long)e * 8);
        float rr[8];
#pragma unroll
        for (int r = 0; r < 8; r++) rr[r] = us2f((u16)r8[r]);
        float hv[16];
#pragma unroll
        for (int q = 0; q < 2; q++) {
            short8 w8 = *reinterpret_cast<const short8*>(Rw1 + jb + q * 8);
#pragma unroll
            for (int j = 0; j < 8; j++) hv[q * 8 + j] = rr[0] * us2f((u16)w8[j]);
        }
#pragma unroll
        for (int r = 1; r < 8; r++) {
#pragma unroll
            for (int q = 0; q < 2; q++) {
                short8 w8 = *reinterpret_cast<const short8*>(Rw1 + (long)r * 64 + jb + q * 8);
#pragma unroll
                for (int j = 0; j < 8; j++) hv[q * 8 + j] += rr[r] * us2f((u16)w8[j]);
            }
        }
#pragma unroll
        for (int q = 0; q < 4; q++) {
            ushort4 pk;
            pk.x = f2us(silu_f(hv[q * 4 + 0] * 0.35355339059327373f));
            pk.y = f2us(silu_f(hv[q * 4 + 1] * 0.35355339059327373f));
            pk.z = f2us(silu_f(hv[q * 4 + 2] * 0.35355339059327373f));
            pk.w = f2us(silu_f(hv[q * 4 + 3] * 0.35355339059327373f));
            *reinterpret_cast<ushort4*>(&hid_s[el][jb + q * 4]) = pk;
        }
    }
    __syncthreads();

    // ---- phase B: hid[64x64] @ Rw2T -> w_lds[64 slots][256] -------------------
    {
        short8 bfr[4][2];
#pragma unroll
        for (int t = 0; t < 4; t++)
#pragma unroll
            for (int s = 0; s < 2; s++)
                bfr[t][s] = *reinterpret_cast<const short8*>(
                    Rw2 + (long)(wv * 64 + t * 16 + llo) * 64 + s * 32 + lhi * 8);
        f32x4 acc[4][4];
#pragma unroll
        for (int i = 0; i < 4; i++)
#pragma unroll
            for (int t = 0; t < 4; t++) acc[i][t] = 0.0f;
#pragma unroll
        for (int s = 0; s < 2; s++) {
            short8 af[4];
#pragma unroll
            for (int i = 0; i < 4; i++)
                af[i] = *reinterpret_cast<const short8*>(&hid_s[i * 16 + llo][s * 32 + lhi * 8]);
#pragma unroll
            for (int i = 0; i < 4; i++)
#pragma unroll
                for (int t = 0; t < 4; t++)
                    acc[i][t] = __builtin_amdgcn_mfma_f32_16x16x32_bf16(af[i], bfr[t][s], acc[i][t], 0, 0, 0);
        }
        __syncthreads();     // all hid reads done; safe to overwrite region with w
#pragma unroll
        for (int i = 0; i < 4; i++)
#pragma unroll
            for (int t = 0; t < 4; t++)
#pragma unroll
                for (int r = 0; r < 4; r++)
                    w_lds[(i * 16 + lhi * 4 + r) * RROW + wv * 64 + t * 16 + llo] =
                        f2us(acc[i][t][r] * 0.125f);
    }
    __syncthreads();

    // ---- phase C: messages + segmented atomic reduction (prefetch depth 2) ----
    {
        const float qn = 0.25f;                 // 1/sqrt(avg_neigh)
        const float rs3 = 0.57735026918962576f; // 1/sqrt(3)
        int l = lane;
        int base = wv * 16;
        float acc[8];
#pragma unroll
        for (int r = 0; r < 8; r++) acc[r] = 0.f;
        int cur = -1;

        int4 ma = meta[p0 + base];
        ushort4 ha = *reinterpret_cast<const ushort4*>(h + (long)ma.x * 256 + l * 4);
        int4 mb_ = meta[p0 + base + 1];
        ushort4 hb = *reinterpret_cast<const ushort4*>(h + (long)mb_.x * 256 + l * 4);

        for (int ss = 0; ss < 16; ss++) {
            int4 mc = mb_; ushort4 hc = hb;
            if (ss + 2 < 16) {
                mc = meta[p0 + base + ss + 2];
                hc = *reinterpret_cast<const ushort4*>(h + (long)mc.x * 256 + l * 4);
            }
            int node = (int)(((unsigned)ma.w) >> 18);
            if (node != cur) {                       // wave-uniform branch
                if (cur >= 0) {
                    float* dst = abuf32 + (long)cur * 512 + l;
                    atomicAdd(dst,        acc[0] * qn);
                    atomicAdd(dst + 64,   acc[1] * qn * rs3);
                    atomicAdd(dst + 128,  acc[2] * qn);
                    atomicAdd(dst + 192,  acc[3] * qn);
                    atomicAdd(dst + 256,  acc[4] * qn);
                    atomicAdd(dst + 320,  acc[5] * qn);
                    atomicAdd(dst + 384,  acc[6] * qn);
                    atomicAdd(dst + 448,  acc[7] * qn);
                }
                cur = node;
#pragma unroll
                for (int r = 0; r < 8; r++) acc[r] = 0.f;
            }
            int sl = base + ss;
            float w0 = us2f(w_lds[sl * RROW + l]);
            float w1 = us2f(w_lds[sl * RROW + 64 + l]);
            float w2 = us2f(w_lds[sl * RROW + 128 + l]);
            float w3 = us2f(w_lds[sl * RROW + 192 + l]);
            float y0  = us2f((u16)((unsigned)ma.y & 0xffff));
            float y1x = us2f((u16)((unsigned)ma.y >> 16));
            float y1y = us2f((u16)((unsigned)ma.z & 0xffff));
            float y1z = us2f((u16)((unsigned)ma.z >> 16));
            float s0 = us2f(ha.x), s1x = us2f(ha.y), s1y = us2f(ha.z), s1z = us2f(ha.w);
            acc[0] += w0 * s0 * y0;
            acc[1] += w1 * (s1x * y1x + s1y * y1y + s1z * y1z);
            acc[2] += w2 * s0 * y1x;  acc[3] += w3 * s1x * y0;
            acc[4] += w2 * s0 * y1y;  acc[5] += w3 * s1y * y0;
            acc[6] += w2 * s0 * y1z;  acc[7] += w3 * s1z * y0;
            ma = mb_; ha = hb; mb_ = mc; hb = hc;
        }
        {
            float* dst = abuf32 + (long)cur * 512 + l;
            atomicAdd(dst,        acc[0] * qn);
            atomicAdd(dst + 64,   acc[1] * qn * rs3);
            atomicAdd(dst + 128,  acc[2] * qn);
            atomicAdd(dst + 192,  acc[3] * qn);
            atomicAdd(dst + 256,  acc[4] * qn);
            atomicAdd(dst + 320,  acc[5] * qn);
            atomicAdd(dst + 384,  acc[6] * qn);
            atomicAdd(dst + 448,  acc[7] * qn);
        }
    }
}

// ---------------- linear_down + species sc + gate (MFMA) ------------------------
// Block = 32 nodes, 5 waves: wave g = output group {scal, gate, vx, vy, vz}.
// A-operand for the down-GEMM comes from f32 abuf32 (converted to bf16 in-reg,
// same rounding point as the old bf16 abuf). Vector outputs staged in LDS and
// written as fully-coalesced float4.
#define DN 32
__global__ void __launch_bounds__(320, 3)
k_down(const float* __restrict__ abuf32, const u16* __restrict__ x0,
       const u16* __restrict__ x1T, const int* __restrict__ species,
       const u16* __restrict__ Wd0T, const u16* __restrict__ Wd1T,
       const u16* __restrict__ Wsc0T, const u16* __restrict__ Wsc1T,
       float* __restrict__ out) {
    __shared__ float gate_s[DN][65];
    __shared__ float vec_s[DN * 192];       // raw f1 in output order [row][col*3+c]
    __shared__ int sp_s[DN];
    int tid = threadIdx.x;
    int g = tid >> 6;
    int lane = tid & 63, lhi = lane >> 4, llo = lane & 15;
    int node0 = blockIdx.x * DN;
    if (tid < DN) sp_s[tid] = species[node0 + tid];
    __syncthreads();

    const float* Ad; const u16* BdT; int bcol;
    const u16* As; const u16* BsT; int sstr;
    if (g <= 1) { Ad = abuf32; BdT = Wd0T; bcol = g * 64; As = x0; BsT = Wsc0T; sstr = 8192; }
    else        { Ad = abuf32 + (g - 1) * 128; BdT = Wd1T; bcol = 0;
                  As = x1T + (long)(g - 2) * N64; BsT = Wsc1T; sstr = 4096; }

    const float inv2 = 0.08838834764831845f;  // 1/sqrt(128)
    const float inv  = 0.125f;                // 1/sqrt(64)

    // ---- self-connection phase: all species, row-select -----------------------
    short8 a2[DN / 16][2];
#pragma unroll
    for (int rt = 0; rt < DN / 16; rt++)
#pragma unroll
        for (int ks = 0; ks < 2; ks++)
            a2[rt][ks] = *reinterpret_cast<const short8*>(
                As + (long)(node0 + rt * 16 + llo) * 64 + ks * 32 + lhi * 8);

    f32x4 res[DN / 16][4];
#pragma unroll
    for (int rt = 0; rt < DN / 16; rt++)
#pragma unroll
        for (int ct = 0; ct < 4; ct++) res[rt][ct] = 0.0f;

    for (int s = 0; s < 4; s++) {
        short8 bs[4][2];
#pragma unroll
        for (int ct = 0; ct < 4; ct++)
#pragma unroll
            for (int ks = 0; ks < 2; ks++)
                bs[ct][ks] = *reinterpret_cast<const short8*>(
                    BsT + (long)s * sstr + (long)(bcol + ct * 16 + llo) * 64 + ks * 32 + lhi * 8);
#pragma unroll
        for (int rt = 0; rt < DN / 16; rt++) {
            f32x4 accs[4];
#pragma unroll
            for (int ct = 0; ct < 4; ct++) accs[ct] = 0.0f;
#pragma unroll
            for (int ks = 0; ks < 2; ks++)
#pragma unroll
                for (int ct = 0; ct < 4; ct++)
                    accs[ct] = __builtin_amdgcn_mfma_f32_16x16x32_bf16(a2[rt][ks], bs[ct][ks], accs[ct], 0, 0, 0);
#pragma unroll
            for (int r = 0; r < 4; r++) {
                int sp = sp_s[rt * 16 + lhi * 4 + r];
                if (sp == s)
#pragma unroll
                    for (int ct = 0; ct < 4; ct++) res[rt][ct][r] = accs[ct][r];
            }
        }
    }

    // ---- linear_down phase -----------------------------------------------------
    short8 bd[4][4];
#pragma unroll
    for (int ct = 0; ct < 4; ct++)
#pragma unroll
        for (int ks = 0; ks < 4; ks++)
            bd[ct][ks] = *reinterpret_cast<const short8*>(
                BdT + (long)(bcol + ct * 16 + llo) * 128 + ks * 32 + lhi * 8);

#pragma unroll
    for (int rt = 0; rt < DN / 16; rt++) {
        f32x4 accd[4];
#pragma unroll
        for (int ct = 0; ct < 4; ct++) accd[ct] = 0.0f;
#pragma unroll
        for (int ks = 0; ks < 4; ks++) {
            short8 a = f32x8_to_bf16(Ad + (long)(node0 + rt * 16 + llo) * 512 + ks * 32 + lhi * 8);
#pragma unroll
            for (int ct = 0; ct < 4; ct++)
                accd[ct] = __builtin_amdgcn_mfma_f32_16x16x32_bf16(a, bd[ct][ks], accd[ct], 0, 0, 0);
        }
#pragma unroll
        for (int ct = 0; ct < 4; ct++)
#pragma unroll
            for (int r = 0; r < 4; r++) {
                float fvv = 0.5f * (accd[ct][r] * inv2 + res[rt][ct][r] * inv);
                int row = rt * 16 + lhi * 4 + r;
                int col = ct * 16 + llo;
                if (g == 0) {
                    out[(long)(node0 + row) * 64 + col] = silu_f(fvv);
                } else if (g == 1) {
                    gate_s[row][col] = silu_f(fvv);
                } else {
                    vec_s[row * 192 + col * 3 + (g - 2)] = fvv;
                }
            }
    }
    __syncthreads();

    // ---- cooperative coalesced vector store (gate applied here) ---------------
    {
        float* vout = out + (long)N64 + (long)node0 * 192;
        for (int q4 = tid; q4 < DN * 48; q4 += 320) {
            int q = q4 * 4;
            int row = q4 / 48;                // 48 float4 per node row
            int rem = q - row * 192;
            f32x4 v = *reinterpret_cast<const f32x4*>(&vec_s[q]);
#pragma unroll
            for (int e = 0; e < 4; e++) v[e] *= gate_s[row][(rem + e) / 3];
            *reinterpret_cast<f32x4*>(vout + q) = v;
        }
    }
}

// ---------------- host launch --------------------------------------------------
extern "C" void kernel_launch(void* const* d_in, const int* in_sizes, int n_in,
                              void* d_out, int out_size, void* d_ws, size_t ws_size,
                              hipStream_t stream) {
    const int* senders   = (const int*)d_in[5];
    const int* receivers = (const int*)d_in[6];
    const int* species   = (const int*)d_in[7];
    float* out = (float*)d_out;

    char* ws = (char*)d_ws;
    size_t o = 0;
    auto alloc = [&](size_t bytes) { size_t p = o; o = (o + bytes + 255) & ~255UL; return p; };
    int* flag   = (int*)(ws + alloc(4));
    int* cnt    = (int*)(ws + alloc((size_t)NN * 4));
    int* offs   = (int*)(ws + alloc((size_t)(NN + 1) * 4));
    int* cursor = (int*)(ws + alloc((size_t)NN * 4));
    int4* meta  = (int4*)(ws + alloc((size_t)NE * 16));
    u16* c_x0   = (u16*)(ws + alloc(SB0 * 2));
    u16* x1T    = (u16*)(ws + alloc((size_t)3 * N64 * 2));
    u16* c_ey0  = (u16*)(ws + alloc((SB2 - SB1) * 2));
    u16* c_ey1  = (u16*)(ws + alloc((SB3 - SB2) * 2));
    u16* c_re   = (u16*)(ws + alloc((SB4 - SB3) * 2));
    u16* c_Wup0 = (u16*)(ws + alloc((SB5 - SB4) * 2));
    u16* c_Wup1 = (u16*)(ws + alloc((SB6 - SB5) * 2));
    u16* c_Rw1  = (u16*)(ws + alloc((SB7 - SB6) * 2));
    u16* c_Rw2  = (u16*)(ws + alloc((SB8 - SB7) * 2));
    u16* c_Wd0  = (u16*)(ws + alloc((SB9 - SB8) * 2));
    u16* c_Wd1  = (u16*)(ws + alloc((SB10 - SB9) * 2));
    u16* c_Wsc0 = (u16*)(ws + alloc((SB11 - SB10) * 2));
    u16* c_Wsc1 = (u16*)(ws + alloc((SB12 - SB11) * 2));
    u16* h      = (u16*)(ws + alloc((size_t)NN * 256 * 2));   // [node][64][4]
    float* abuf32 = (float*)(ws + alloc((size_t)NN * 512 * 4)); // [node][512] f32

    k_sniff<<<1, 64, 0, stream>>>((const u16*)d_in[4], flag);
    (void)hipMemsetAsync(cnt, 0, (size_t)NN * 4, stream);
    (void)hipMemsetAsync(abuf32, 0, (size_t)NN * 512 * 4, stream);
    k_convert<<<29058, 256, 0, stream>>>(d_in[0], d_in[1], d_in[2], d_in[3], d_in[4],
        d_in[8], d_in[9], d_in[10], d_in[11], d_in[12], d_in[13], d_in[14], d_in[15],
        flag, receivers, cnt,
        c_x0, x1T, c_ey0, c_ey1, c_re,
        c_Wup0, c_Wup1, c_Rw1, c_Rw2, c_Wd0, c_Wd1, c_Wsc0, c_Wsc1);
    k_scan<<<1, 256, 0, stream>>>(cnt, offs, cursor);
    k_scatter<<<NE / 256, 256, 0, stream>>>(receivers, senders, c_ey0, c_ey1,
                                            cursor, meta);

    k_up_gemm<<<dim3(NN / 256, 4), 256, 0, stream>>>(c_x0, x1T, c_Wup0, c_Wup1, h);

    k_edge<<<NE / 64, 256, 0, stream>>>(c_re, c_Rw1, c_Rw2, meta, h, abuf32);

    k_down<<<NN / DN, 320, 0, stream>>>(abuf32, c_x0, x1T, species,
                                        c_Wd0, c_Wd1, c_Wsc0, c_Wsc1, out);
}

// Round 7
// 266.567 us; speedup vs baseline: 1.6054x; 1.0113x over previous
//
#include <hip/hip_runtime.h>

#define NN 16384          // nodes
#define NE 262144         // edges
#define N64 (NN * 64)

typedef unsigned short u16;
typedef __attribute__((ext_vector_type(8))) short short8;
typedef __attribute__((ext_vector_type(4))) float f32x4;

__device__ __forceinline__ float us2f(u16 u) {
    union { unsigned int i; float f; } v; v.i = ((unsigned int)u) << 16; return v.f;
}
__device__ __forceinline__ u16 f2us(float x) {   // f32 -> bf16 bits, RNE
    union { float f; unsigned int i; } u; u.f = x;
    unsigned int r = u.i + 0x7FFF + ((u.i >> 16) & 1);
    return (u16)(r >> 16);
}
__device__ __forceinline__ float silu_f(float x) { return x / (1.0f + __expf(-x)); }
__device__ __forceinline__ float ldf(const void* p, long i, int f) {
    return f ? ((const float*)p)[i] : us2f(((const u16*)p)[i]);
}
__device__ __forceinline__ void ld8(const void* p, long v8, int f, float* o) {
    if (f) {
        const f32x4* q = (const f32x4*)p + v8 * 2;
        f32x4 a = q[0], b = q[1];
        o[0] = a[0]; o[1] = a[1]; o[2] = a[2]; o[3] = a[3];
        o[4] = b[0]; o[5] = b[1]; o[6] = b[2]; o[7] = b[3];
    } else {
        short8 s = ((const short8*)p)[v8];
#pragma unroll
        for (int j = 0; j < 8; j++) o[j] = us2f((u16)s[j]);
    }
}
__device__ __forceinline__ void st8(u16* d, const float* o) {
    short8 s;
#pragma unroll
    for (int j = 0; j < 8; j++) s[j] = (short)f2us(o[j]);
    *reinterpret_cast<short8*>(d) = s;
}
__device__ __forceinline__ short8 f32x8_to_bf16(const float* p) {
    f32x4 a = *reinterpret_cast<const f32x4*>(p);
    f32x4 b = *reinterpret_cast<const f32x4*>(p + 4);
    short8 r;
    r[0] = (short)f2us(a[0]); r[1] = (short)f2us(a[1]);
    r[2] = (short)f2us(a[2]); r[3] = (short)f2us(a[3]);
    r[4] = (short)f2us(b[0]); r[5] = (short)f2us(b[1]);
    r[6] = (short)f2us(b[2]); r[7] = (short)f2us(b[3]);
    return r;
}

// ---------------- dtype sniff (drives only k_convert) --------------------------
__global__ void k_sniff(const u16* __restrict__ re, int* __restrict__ flag) {
    int t = threadIdx.x;
    int hit = (re[t] >= 0x4000) ? 1 : 0;
    unsigned long long b = __ballot(hit);
    if (t == 0) *flag = (__popcll(b) >= 4) ? 1 : 0;   // 1 => f32 inputs
}

// ---------------- convert all float tensors to bf16 + x1 transpose + hist ------
// Vectorized: big tensors 8 elems/thread (x1: 24/thread -> 3 coalesced plane
// stores); weights scalar. Thread budget:
//   [0,131072)        x0   x8
//   [131072,262144)   x1   x24
//   [262144,294912)   ey0  x8
//   [294912,393216)   ey1  x8
//   [393216,655360)   re   x8
//   [655360,754176)   weights x1 (transposed layouts, see below)
// Weight layouts (consumed as MFMA B-operands, single short8 fragment loads):
//   c_Wup0/c_Wup1 : [k_out=64][m=64]   c_Rw2 : [k_out=256][m=64]
//   c_Wd0 : [n=128][k=128]  c_Wd1 : [n=64][k=128]
//   c_Wsc0 : [s][n=128][m=64]  c_Wsc1 : [s][n=64][m=64]
// SB macros retained for host-side allocation sizing.
#define SB0 1048576L
#define SB1 4194304L
#define SB2 4456448L
#define SB3 5242880L
#define SB4 7340032L
#define SB5 7344128L
#define SB6 7348224L
#define SB7 7348736L
#define SB8 7365120L
#define SB9 7381504L
#define SB10 7389696L
#define SB11 7422464L
#define SB12 7438848L

__global__ void k_convert(const void* x0, const void* x1, const void* ey0, const void* ey1,
                          const void* re, const void* Wup0, const void* Wup1, const void* Rw1,
                          const void* Rw2, const void* Wd0, const void* Wd1, const void* Wsc0,
                          const void* Wsc1, const int* __restrict__ flag,
                          const int* __restrict__ recv, int* __restrict__ cnt,
                          u16* c_x0, u16* x1T, u16* c_ey0, u16* c_ey1, u16* c_re,
                          u16* c_Wup0, u16* c_Wup1, u16* c_Rw1, u16* c_Rw2,
                          u16* c_Wd0, u16* c_Wd1, u16* c_Wsc0, u16* c_Wsc1) {
    long i = (long)blockIdx.x * 256 + threadIdx.x;
    int f = *flag;
    if (i < NE) atomicAdd(&cnt[recv[i]], 1);          // fused histogram
    if (i < 131072) {
        float o[8]; ld8(x0, i, f, o); st8(c_x0 + i * 8, o);
    } else if (i < 262144) {
        long v = i - 131072;
        int n = (int)(v >> 3), k8 = (int)(v & 7);
        long b8 = (long)n * 24 + (long)k8 * 3;
        float o[24];
        ld8(x1, b8, f, o); ld8(x1, b8 + 1, f, o + 8); ld8(x1, b8 + 2, f, o + 16);
#pragma unroll
        for (int c = 0; c < 3; c++) {
            float t[8];
#pragma unroll
            for (int k = 0; k < 8; k++) t[k] = o[k * 3 + c];
            st8(x1T + (long)c * N64 + (long)n * 64 + k8 * 8, t);
        }
    } else if (i < 294912) {
        long v = i - 262144; float o[8]; ld8(ey0, v, f, o); st8(c_ey0 + v * 8, o);
    } else if (i < 393216) {
        long v = i - 294912; float o[8]; ld8(ey1, v, f, o); st8(c_ey1 + v * 8, o);
    } else if (i < 655360) {
        long v = i - 393216; float o[8]; ld8(re, v, f, o); st8(c_re + v * 8, o);
    } else {
        long t = i - 655360;
        if (t < 4096)       { long r = t >> 6, c = t & 63;
                              c_Wup0[c * 64 + r] = f2us(ldf(Wup0, t, f)); }
        else if (t < 8192)  { t -= 4096; long r = t >> 6, c = t & 63;
                              c_Wup1[c * 64 + r] = f2us(ldf(Wup1, t, f)); }
        else if (t < 8704)  { t -= 8192; c_Rw1[t] = f2us(ldf(Rw1, t, f)); }
        else if (t < 25088) { t -= 8704; long r = t >> 8, c = t & 255;
                              c_Rw2[c * 64 + r] = f2us(ldf(Rw2, t, f)); }
        else if (t < 41472) { t -= 25088; long r = t >> 7, c = t & 127;
                              c_Wd0[c * 128 + r] = f2us(ldf(Wd0, t, f)); }
        else if (t < 49664) { t -= 41472; long r = t >> 6, c = t & 63;
                              c_Wd1[c * 128 + r] = f2us(ldf(Wd1, t, f)); }
        else if (t < 82432) { t -= 49664; long s = t >> 13, rm = t & 8191;
                              long r = rm >> 7, c = rm & 127;
                              c_Wsc0[s * 8192 + c * 64 + r] = f2us(ldf(Wsc0, t, f)); }
        else                { t -= 82432; long s = t >> 12, rm = t & 4095;
                              long r = rm >> 6, c = rm & 63;
                              c_Wsc1[s * 4096 + c * 64 + r] = f2us(ldf(Wsc1, t, f)); }
    }
}

// ---------------- CSR scan + scatter -------------------------------------------
__global__ void k_scan(const int* __restrict__ cnt, int* __restrict__ offs,
                       int* __restrict__ cursor) {
    __shared__ int sd[256];
    int t = threadIdx.x;
    int base = t * 64;
    const int4* c4 = (const int4*)cnt;
    int loc[64];
#pragma unroll
    for (int i = 0; i < 16; i++) {
        int4 v = c4[t * 16 + i];
        loc[i * 4 + 0] = v.x; loc[i * 4 + 1] = v.y; loc[i * 4 + 2] = v.z; loc[i * 4 + 3] = v.w;
    }
    int sum = 0;
#pragma unroll
    for (int i = 0; i < 64; i++) sum += loc[i];
    sd[t] = sum; __syncthreads();
    for (int off = 1; off < 256; off <<= 1) {
        int v = (t >= off) ? sd[t - off] : 0;
        __syncthreads();
        sd[t] += v;
        __syncthreads();
    }
    int run = sd[t] - sum;
    for (int i = 0; i < 64; i++) {
        offs[base + i] = run; cursor[base + i] = run;
        run += loc[i];
    }
    if (t == 255) offs[NN] = run;
}

// meta.w packs edge id (18 bits) | receiver node (14 bits) -------------------
__global__ void k_scatter(const int* __restrict__ recv, const int* __restrict__ senders,
                          const u16* __restrict__ ey0, const u16* __restrict__ ey1,
                          int* __restrict__ cursor, int4* __restrict__ meta) {
    int e = blockIdx.x * 256 + threadIdx.x;
    int node = recv[e];
    int p = atomicAdd(&cursor[node], 1);
    unsigned y0  = ey0[e];
    unsigned y1x = ey1[(long)e * 3 + 0];
    unsigned y1y = ey1[(long)e * 3 + 1];
    unsigned y1z = ey1[(long)e * 3 + 2];
    int4 m;
    m.x = senders[e];
    m.y = (int)(y0 | (y1x << 16));
    m.z = (int)(y1y | (y1z << 16));
    m.w = (int)((unsigned)e | ((unsigned)node << 18));
    meta[p] = m;
}

// ---------------- linear_up: h[node][64ch][4comp] interleaved bf16 --------------
__global__ void k_up_gemm(const u16* __restrict__ x0, const u16* __restrict__ x1T,
                          const u16* __restrict__ Wup0, const u16* __restrict__ Wup1,
                          u16* __restrict__ h) {
    int inst = blockIdx.y;
    int wv = threadIdx.x >> 6, lane = threadIdx.x & 63;
    int lhi = lane >> 4, llo = lane & 15;
    int mb = blockIdx.x * 256 + wv * 64;
    const u16* B = (inst == 0) ? Wup0 : Wup1;     // transposed [k_out=64][m=64]
    const u16* A = (inst == 0) ? x0 : (x1T + (long)(inst - 1) * N64);

    short8 bfr[4][2];
#pragma unroll
    for (int t = 0; t < 4; t++)
#pragma unroll
        for (int s = 0; s < 2; s++)
            bfr[t][s] = *reinterpret_cast<const short8*>(B + (long)(t * 16 + llo) * 64 + s * 32 + lhi * 8);

    f32x4 acc[4][4];
#pragma unroll
    for (int i = 0; i < 4; i++)
#pragma unroll
        for (int t = 0; t < 4; t++) acc[i][t] = 0.0f;

#pragma unroll
    for (int s = 0; s < 2; s++) {
        short8 af[4];
#pragma unroll
        for (int i = 0; i < 4; i++)
            af[i] = *reinterpret_cast<const short8*>(A + (long)(mb + i * 16 + llo) * 64 + s * 32 + lhi * 8);
#pragma unroll
        for (int i = 0; i < 4; i++)
#pragma unroll
            for (int t = 0; t < 4; t++)
                acc[i][t] = __builtin_amdgcn_mfma_f32_16x16x32_bf16(af[i], bfr[t][s], acc[i][t], 0, 0, 0);
    }
#pragma unroll
    for (int i = 0; i < 4; i++)
#pragma unroll
        for (int t = 0; t < 4; t++)
#pragma unroll
            for (int r = 0; r < 4; r++)
                h[(long)(mb + i * 16 + lhi * 4 + r) * 256 + (t * 16 + llo) * 4 + inst] =
                    f2us(acc[i][t][r] * 0.125f);
}

// ---------------- fused radial MLP + tensor-product gather (CSR-ordered) --------
// Round-6 structure with RROW 268 -> 256: LDS 32768 B = exactly 5 blocks/CU
// (was 4). Costs a 4-way bank conflict on phase-B's 16 u16 stores/thread;
// phase-C reads (64/thread) remain conflict-free.
#define RROW 256
__global__ void __launch_bounds__(256, 5)
k_edge(const u16* __restrict__ re, const u16* __restrict__ Rw1,
       const u16* __restrict__ Rw2, const int4* __restrict__ meta,
       const u16* __restrict__ h, float* __restrict__ abuf32) {
    __shared__ u16 w_lds[64 * RROW];          // 32768 B; hid aliased below
    u16 (*hid_s)[72] = reinterpret_cast<u16 (*)[72]>(w_lds);

    int tid = threadIdx.x;
    int wv = tid >> 6, lane = tid & 63, lhi = lane >> 4, llo = lane & 15;
    int p0 = blockIdx.x * 64;

    // ---- phase A: radial hidden layer for this block's 64 CSR slots ----------
    {
        int el = tid >> 2;
        int jb = (tid & 3) * 16;
        int e = ((const int*)meta)[(long)(p0 + el) * 4 + 3] & 0x3FFFF;
        short8 r8 = *reinterpret_cast<const short8*>(re + (long)e * 8);
        float rr[8];
#pragma unroll
        for (int r = 0; r < 8; r++) rr[r] = us2f((u16)r8[r]);
        float hv[16];
#pragma unroll
        for (int q = 0; q < 2; q++) {
            short8 w8 = *reinterpret_cast<const short8*>(Rw1 + jb + q * 8);
#pragma unroll
            for (int j = 0; j < 8; j++) hv[q * 8 + j] = rr[0] * us2f((u16)w8[j]);
        }
#pragma unroll
        for (int r = 1; r < 8; r++) {
#pragma unroll
            for (int q = 0; q < 2; q++) {
                short8 w8 = *reinterpret_cast<const short8*>(Rw1 + (long)r * 64 + jb + q * 8);
#pragma unroll
                for (int j = 0; j < 8; j++) hv[q * 8 + j] += rr[r] * us2f((u16)w8[j]);
            }
        }
#pragma unroll
        for (int q = 0; q < 4; q++) {
            ushort4 pk;
            pk.x = f2us(silu_f(hv[q * 4 + 0] * 0.35355339059327373f));
            pk.y = f2us(silu_f(hv[q * 4 + 1] * 0.35355339059327373f));
            pk.z = f2us(silu_f(hv[q * 4 + 2] * 0.35355339059327373f));
            pk.w = f2us(silu_f(hv[q * 4 + 3] * 0.35355339059327373f));
            *reinterpret_cast<ushort4*>(&hid_s[el][jb + q * 4]) = pk;
        }
    }
    __syncthreads();

    // ---- phase B: hid[64x64] @ Rw2T -> w_lds[64 slots][256] -------------------
    {
        short8 bfr[4][2];
#pragma unroll
        for (int t = 0; t < 4; t++)
#pragma unroll
            for (int s = 0; s < 2; s++)
                bfr[t][s] = *reinterpret_cast<const short8*>(
                    Rw2 + (long)(wv * 64 + t * 16 + llo) * 64 + s * 32 + lhi * 8);
        f32x4 acc[4][4];
#pragma unroll
        for (int i = 0; i < 4; i++)
#pragma unroll
            for (int t = 0; t < 4; t++) acc[i][t] = 0.0f;
#pragma unroll
        for (int s = 0; s < 2; s++) {
            short8 af[4];
#pragma unroll
            for (int i = 0; i < 4; i++)
                af[i] = *reinterpret_cast<const short8*>(&hid_s[i * 16 + llo][s * 32 + lhi * 8]);
#pragma unroll
            for (int i = 0; i < 4; i++)
#pragma unroll
                for (int t = 0; t < 4; t++)
                    acc[i][t] = __builtin_amdgcn_mfma_f32_16x16x32_bf16(af[i], bfr[t][s], acc[i][t], 0, 0, 0);
        }
        __syncthreads();     // all hid reads done; safe to overwrite region with w
#pragma unroll
        for (int i = 0; i < 4; i++)
#pragma unroll
            for (int t = 0; t < 4; t++)
#pragma unroll
                for (int r = 0; r < 4; r++)
                    w_lds[(i * 16 + lhi * 4 + r) * RROW + wv * 64 + t * 16 + llo] =
                        f2us(acc[i][t][r] * 0.125f);
    }
    __syncthreads();

    // ---- phase C: messages + segmented atomic reduction (prefetch depth 2) ----
    {
        const float qn = 0.25f;                 // 1/sqrt(avg_neigh)
        const float rs3 = 0.57735026918962576f; // 1/sqrt(3)
        int l = lane;
        int base = wv * 16;
        float acc[8];
#pragma unroll
        for (int r = 0; r < 8; r++) acc[r] = 0.f;
        int cur = -1;

        int4 ma = meta[p0 + base];
        ushort4 ha = *reinterpret_cast<const ushort4*>(h + (long)ma.x * 256 + l * 4);
        int4 mb_ = meta[p0 + base + 1];
        ushort4 hb = *reinterpret_cast<const ushort4*>(h + (long)mb_.x * 256 + l * 4);

        for (int ss = 0; ss < 16; ss++) {
            int4 mc = mb_; ushort4 hc = hb;
            if (ss + 2 < 16) {
                mc = meta[p0 + base + ss + 2];
                hc = *reinterpret_cast<const ushort4*>(h + (long)mc.x * 256 + l * 4);
            }
            int node = (int)(((unsigned)ma.w) >> 18);
            if (node != cur) {                       // wave-uniform branch
                if (cur >= 0) {
                    float* dst = abuf32 + (long)cur * 512 + l;
                    atomicAdd(dst,        acc[0] * qn);
                    atomicAdd(dst + 64,   acc[1] * qn * rs3);
                    atomicAdd(dst + 128,  acc[2] * qn);
                    atomicAdd(dst + 192,  acc[3] * qn);
                    atomicAdd(dst + 256,  acc[4] * qn);
                    atomicAdd(dst + 320,  acc[5] * qn);
                    atomicAdd(dst + 384,  acc[6] * qn);
                    atomicAdd(dst + 448,  acc[7] * qn);
                }
                cur = node;
#pragma unroll
                for (int r = 0; r < 8; r++) acc[r] = 0.f;
            }
            int sl = base + ss;
            float w0 = us2f(w_lds[sl * RROW + l]);
            float w1 = us2f(w_lds[sl * RROW + 64 + l]);
            float w2 = us2f(w_lds[sl * RROW + 128 + l]);
            float w3 = us2f(w_lds[sl * RROW + 192 + l]);
            float y0  = us2f((u16)((unsigned)ma.y & 0xffff));
            float y1x = us2f((u16)((unsigned)ma.y >> 16));
            float y1y = us2f((u16)((unsigned)ma.z & 0xffff));
            float y1z = us2f((u16)((unsigned)ma.z >> 16));
            float s0 = us2f(ha.x), s1x = us2f(ha.y), s1y = us2f(ha.z), s1z = us2f(ha.w);
            acc[0] += w0 * s0 * y0;
            acc[1] += w1 * (s1x * y1x + s1y * y1y + s1z * y1z);
            acc[2] += w2 * s0 * y1x;  acc[3] += w3 * s1x * y0;
            acc[4] += w2 * s0 * y1y;  acc[5] += w3 * s1y * y0;
            acc[6] += w2 * s0 * y1z;  acc[7] += w3 * s1z * y0;
            ma = mb_; ha = hb; mb_ = mc; hb = hc;
        }
        {
            float* dst = abuf32 + (long)cur * 512 + l;
            atomicAdd(dst,        acc[0] * qn);
            atomicAdd(dst + 64,   acc[1] * qn * rs3);
            atomicAdd(dst + 128,  acc[2] * qn);
            atomicAdd(dst + 192,  acc[3] * qn);
            atomicAdd(dst + 256,  acc[4] * qn);
            atomicAdd(dst + 320,  acc[5] * qn);
            atomicAdd(dst + 384,  acc[6] * qn);
            atomicAdd(dst + 448,  acc[7] * qn);
        }
    }
}

// ---------------- linear_down + species sc + gate (MFMA) ------------------------
// Block = 32 nodes, 5 waves: wave g = output group {scal, gate, vx, vy, vz}.
// A-operand for the down-GEMM comes from f32 abuf32 (converted to bf16 in-reg).
// Vector outputs staged in LDS and written as fully-coalesced float4.
#define DN 32
__global__ void __launch_bounds__(320, 3)
k_down(const float* __restrict__ abuf32, const u16* __restrict__ x0,
       const u16* __restrict__ x1T, const int* __restrict__ species,
       const u16* __restrict__ Wd0T, const u16* __restrict__ Wd1T,
       const u16* __restrict__ Wsc0T, const u16* __restrict__ Wsc1T,
       float* __restrict__ out) {
    __shared__ float gate_s[DN][65];
    __shared__ float vec_s[DN * 192];       // raw f1 in output order [row][col*3+c]
    __shared__ int sp_s[DN];
    int tid = threadIdx.x;
    int g = tid >> 6;
    int lane = tid & 63, lhi = lane >> 4, llo = lane & 15;
    int node0 = blockIdx.x * DN;
    if (tid < DN) sp_s[tid] = species[node0 + tid];
    __syncthreads();

    const float* Ad; const u16* BdT; int bcol;
    const u16* As; const u16* BsT; int sstr;
    if (g <= 1) { Ad = abuf32; BdT = Wd0T; bcol = g * 64; As = x0; BsT = Wsc0T; sstr = 8192; }
    else        { Ad = abuf32 + (g - 1) * 128; BdT = Wd1T; bcol = 0;
                  As = x1T + (long)(g - 2) * N64; BsT = Wsc1T; sstr = 4096; }

    const float inv2 = 0.08838834764831845f;  // 1/sqrt(128)
    const float inv  = 0.125f;                // 1/sqrt(64)

    // ---- self-connection phase: all species, row-select -----------------------
    short8 a2[DN / 16][2];
#pragma unroll
    for (int rt = 0; rt < DN / 16; rt++)
#pragma unroll
        for (int ks = 0; ks < 2; ks++)
            a2[rt][ks] = *reinterpret_cast<const short8*>(
                As + (long)(node0 + rt * 16 + llo) * 64 + ks * 32 + lhi * 8);

    f32x4 res[DN / 16][4];
#pragma unroll
    for (int rt = 0; rt < DN / 16; rt++)
#pragma unroll
        for (int ct = 0; ct < 4; ct++) res[rt][ct] = 0.0f;

    for (int s = 0; s < 4; s++) {
        short8 bs[4][2];
#pragma unroll
        for (int ct = 0; ct < 4; ct++)
#pragma unroll
            for (int ks = 0; ks < 2; ks++)
                bs[ct][ks] = *reinterpret_cast<const short8*>(
                    BsT + (long)s * sstr + (long)(bcol + ct * 16 + llo) * 64 + ks * 32 + lhi * 8);
#pragma unroll
        for (int rt = 0; rt < DN / 16; rt++) {
            f32x4 accs[4];
#pragma unroll
            for (int ct = 0; ct < 4; ct++) accs[ct] = 0.0f;
#pragma unroll
            for (int ks = 0; ks < 2; ks++)
#pragma unroll
                for (int ct = 0; ct < 4; ct++)
                    accs[ct] = __builtin_amdgcn_mfma_f32_16x16x32_bf16(a2[rt][ks], bs[ct][ks], accs[ct], 0, 0, 0);
#pragma unroll
            for (int r = 0; r < 4; r++) {
                int sp = sp_s[rt * 16 + lhi * 4 + r];
                if (sp == s)
#pragma unroll
                    for (int ct = 0; ct < 4; ct++) res[rt][ct][r] = accs[ct][r];
            }
        }
    }

    // ---- linear_down phase -----------------------------------------------------
    short8 bd[4][4];
#pragma unroll
    for (int ct = 0; ct < 4; ct++)
#pragma unroll
        for (int ks = 0; ks < 4; ks++)
            bd[ct][ks] = *reinterpret_cast<const short8*>(
                BdT + (long)(bcol + ct * 16 + llo) * 128 + ks * 32 + lhi * 8);

#pragma unroll
    for (int rt = 0; rt < DN / 16; rt++) {
        f32x4 accd[4];
#pragma unroll
        for (int ct = 0; ct < 4; ct++) accd[ct] = 0.0f;
#pragma unroll
        for (int ks = 0; ks < 4; ks++) {
            short8 a = f32x8_to_bf16(Ad + (long)(node0 + rt * 16 + llo) * 512 + ks * 32 + lhi * 8);
#pragma unroll
            for (int ct = 0; ct < 4; ct++)
                accd[ct] = __builtin_amdgcn_mfma_f32_16x16x32_bf16(a, bd[ct][ks], accd[ct], 0, 0, 0);
        }
#pragma unroll
        for (int ct = 0; ct < 4; ct++)
#pragma unroll
            for (int r = 0; r < 4; r++) {
                float fvv = 0.5f * (accd[ct][r] * inv2 + res[rt][ct][r] * inv);
                int row = rt * 16 + lhi * 4 + r;
                int col = ct * 16 + llo;
                if (g == 0) {
                    out[(long)(node0 + row) * 64 + col] = silu_f(fvv);
                } else if (g == 1) {
                    gate_s[row][col] = silu_f(fvv);
                } else {
                    vec_s[row * 192 + col * 3 + (g - 2)] = fvv;
                }
            }
    }
    __syncthreads();

    // ---- cooperative coalesced vector store (gate applied here) ---------------
    {
        float* vout = out + (long)N64 + (long)node0 * 192;
        for (int q4 = tid; q4 < DN * 48; q4 += 320) {
            int q = q4 * 4;
            int row = q4 / 48;                // 48 float4 per node row
            int rem = q - row * 192;
            f32x4 v = *reinterpret_cast<const f32x4*>(&vec_s[q]);
#pragma unroll
            for (int e = 0; e < 4; e++) v[e] *= gate_s[row][(rem + e) / 3];
            *reinterpret_cast<f32x4*>(vout + q) = v;
        }
    }
}

// ---------------- host launch --------------------------------------------------
extern "C" void kernel_launch(void* const* d_in, const int* in_sizes, int n_in,
                              void* d_out, int out_size, void* d_ws, size_t ws_size,
                              hipStream_t stream) {
    const int* senders   = (const int*)d_in[5];
    const int* receivers = (const int*)d_in[6];
    const int* species   = (const int*)d_in[7];
    float* out = (float*)d_out;

    char* ws = (char*)d_ws;
    size_t o = 0;
    auto alloc = [&](size_t bytes) { size_t p = o; o = (o + bytes + 255) & ~255UL; return p; };
    int* flag   = (int*)(ws + alloc(4));
    int* cnt    = (int*)(ws + alloc((size_t)NN * 4));
    int* offs   = (int*)(ws + alloc((size_t)(NN + 1) * 4));
    int* cursor = (int*)(ws + alloc((size_t)NN * 4));
    int4* meta  = (int4*)(ws + alloc((size_t)NE * 16));
    u16* c_x0   = (u16*)(ws + alloc(SB0 * 2));
    u16* x1T    = (u16*)(ws + alloc((size_t)3 * N64 * 2));
    u16* c_ey0  = (u16*)(ws + alloc((SB2 - SB1) * 2));
    u16* c_ey1  = (u16*)(ws + alloc((SB3 - SB2) * 2));
    u16* c_re   = (u16*)(ws + alloc((SB4 - SB3) * 2));
    u16* c_Wup0 = (u16*)(ws + alloc((SB5 - SB4) * 2));
    u16* c_Wup1 = (u16*)(ws + alloc((SB6 - SB5) * 2));
    u16* c_Rw1  = (u16*)(ws + alloc((SB7 - SB6) * 2));
    u16* c_Rw2  = (u16*)(ws + alloc((SB8 - SB7) * 2));
    u16* c_Wd0  = (u16*)(ws + alloc((SB9 - SB8) * 2));
    u16* c_Wd1  = (u16*)(ws + alloc((SB10 - SB9) * 2));
    u16* c_Wsc0 = (u16*)(ws + alloc((SB11 - SB10) * 2));
    u16* c_Wsc1 = (u16*)(ws + alloc((SB12 - SB11) * 2));
    u16* h      = (u16*)(ws + alloc((size_t)NN * 256 * 2));   // [node][64][4]
    float* abuf32 = (float*)(ws + alloc((size_t)NN * 512 * 4)); // [node][512] f32

    k_sniff<<<1, 64, 0, stream>>>((const u16*)d_in[4], flag);
    (void)hipMemsetAsync(cnt, 0, (size_t)NN * 4, stream);
    (void)hipMemsetAsync(abuf32, 0, (size_t)NN * 512 * 4, stream);
    k_convert<<<2946, 256, 0, stream>>>(d_in[0], d_in[1], d_in[2], d_in[3], d_in[4],
        d_in[8], d_in[9], d_in[10], d_in[11], d_in[12], d_in[13], d_in[14], d_in[15],
        flag, receivers, cnt,
        c_x0, x1T, c_ey0, c_ey1, c_re,
        c_Wup0, c_Wup1, c_Rw1, c_Rw2, c_Wd0, c_Wd1, c_Wsc0, c_Wsc1);
    k_scan<<<1, 256, 0, stream>>>(cnt, offs, cursor);
    k_scatter<<<NE / 256, 256, 0, stream>>>(receivers, senders, c_ey0, c_ey1,
                                            cursor, meta);

    k_up_gemm<<<dim3(NN / 256, 4), 256, 0, stream>>>(c_x0, x1T, c_Wup0, c_Wup1, h);

    k_edge<<<NE / 64, 256, 0, stream>>>(c_re, c_Rw1, c_Rw2, meta, h, abuf32);

    k_down<<<NN / DN, 320, 0, stream>>>(abuf32, c_x0, x1T, species,
                                        c_Wd0, c_Wd1, c_Wsc0, c_Wsc1, out);
}

// Round 8
// 258.181 us; speedup vs baseline: 1.6575x; 1.0325x over previous
//
#include <hip/hip_runtime.h>

#define NN 16384          // nodes
#define NE 262144         // edges
#define N64 (NN * 64)

typedef unsigned short u16;
typedef __attribute__((ext_vector_type(8))) short short8;
typedef __attribute__((ext_vector_type(4))) float f32x4;

__device__ __forceinline__ float us2f(u16 u) {
    union { unsigned int i; float f; } v; v.i = ((unsigned int)u) << 16; return v.f;
}
__device__ __forceinline__ u16 f2us(float x) {   // f32 -> bf16 bits, RNE
    union { float f; unsigned int i; } u; u.f = x;
    unsigned int r = u.i + 0x7FFF + ((u.i >> 16) & 1);
    return (u16)(r >> 16);
}
__device__ __forceinline__ float silu_f(float x) { return x / (1.0f + __expf(-x)); }
__device__ __forceinline__ float ldf(const void* p, long i, int f) {
    return f ? ((const float*)p)[i] : us2f(((const u16*)p)[i]);
}
__device__ __forceinline__ void ld8(const void* p, long v8, int f, float* o) {
    if (f) {
        const f32x4* q = (const f32x4*)p + v8 * 2;
        f32x4 a = q[0], b = q[1];
        o[0] = a[0]; o[1] = a[1]; o[2] = a[2]; o[3] = a[3];
        o[4] = b[0]; o[5] = b[1]; o[6] = b[2]; o[7] = b[3];
    } else {
        short8 s = ((const short8*)p)[v8];
#pragma unroll
        for (int j = 0; j < 8; j++) o[j] = us2f((u16)s[j]);
    }
}
__device__ __forceinline__ void st8(u16* d, const float* o) {
    short8 s;
#pragma unroll
    for (int j = 0; j < 8; j++) s[j] = (short)f2us(o[j]);
    *reinterpret_cast<short8*>(d) = s;
}
__device__ __forceinline__ short8 f32x8_to_bf16(const float* p) {
    f32x4 a = *reinterpret_cast<const f32x4*>(p);
    f32x4 b = *reinterpret_cast<const f32x4*>(p + 4);
    short8 r;
    r[0] = (short)f2us(a[0]); r[1] = (short)f2us(a[1]);
    r[2] = (short)f2us(a[2]); r[3] = (short)f2us(a[3]);
    r[4] = (short)f2us(b[0]); r[5] = (short)f2us(b[1]);
    r[6] = (short)f2us(b[2]); r[7] = (short)f2us(b[3]);
    return r;
}

// ---------------- dtype sniff (drives only k_convert) --------------------------
__global__ void k_sniff(const u16* __restrict__ re, int* __restrict__ flag) {
    int t = threadIdx.x;
    int hit = (re[t] >= 0x4000) ? 1 : 0;
    unsigned long long b = __ballot(hit);
    if (t == 0) *flag = (__popcll(b) >= 4) ? 1 : 0;   // 1 => f32 inputs
}

// ---------------- convert all float tensors to bf16 + x1 transpose + hist ------
// Vectorized: big tensors 8 elems/thread (x1: 24/thread -> 3 coalesced plane
// stores); weights scalar. Thread budget:
//   [0,131072)        x0   x8
//   [131072,262144)   x1   x24
//   [262144,294912)   ey0  x8
//   [294912,393216)   ey1  x8
//   [393216,655360)   re   x8
//   [655360,754176)   weights x1 (transposed layouts, see below)
// Weight layouts (consumed as MFMA B-operands, single short8 fragment loads):
//   c_Wup0/c_Wup1 : [k_out=64][m=64]   c_Rw2 : [k_out=256][m=64]
//   c_Wd0 : [n=128][k=128]  c_Wd1 : [n=64][k=128]
//   c_Wsc0 : [s][n=128][m=64]  c_Wsc1 : [s][n=64][m=64]
// SB macros retained for host-side allocation sizing.
#define SB0 1048576L
#define SB1 4194304L
#define SB2 4456448L
#define SB3 5242880L
#define SB4 7340032L
#define SB5 7344128L
#define SB6 7348224L
#define SB7 7348736L
#define SB8 7365120L
#define SB9 7381504L
#define SB10 7389696L
#define SB11 7422464L
#define SB12 7438848L

__global__ void k_convert(const void* x0, const void* x1, const void* ey0, const void* ey1,
                          const void* re, const void* Wup0, const void* Wup1, const void* Rw1,
                          const void* Rw2, const void* Wd0, const void* Wd1, const void* Wsc0,
                          const void* Wsc1, const int* __restrict__ flag,
                          const int* __restrict__ recv, int* __restrict__ cnt,
                          u16* c_x0, u16* x1T, u16* c_ey0, u16* c_ey1, u16* c_re,
                          u16* c_Wup0, u16* c_Wup1, u16* c_Rw1, u16* c_Rw2,
                          u16* c_Wd0, u16* c_Wd1, u16* c_Wsc0, u16* c_Wsc1) {
    long i = (long)blockIdx.x * 256 + threadIdx.x;
    int f = *flag;
    if (i < NE) atomicAdd(&cnt[recv[i]], 1);          // fused histogram
    if (i < 131072) {
        float o[8]; ld8(x0, i, f, o); st8(c_x0 + i * 8, o);
    } else if (i < 262144) {
        long v = i - 131072;
        int n = (int)(v >> 3), k8 = (int)(v & 7);
        long b8 = (long)n * 24 + (long)k8 * 3;
        float o[24];
        ld8(x1, b8, f, o); ld8(x1, b8 + 1, f, o + 8); ld8(x1, b8 + 2, f, o + 16);
#pragma unroll
        for (int c = 0; c < 3; c++) {
            float t[8];
#pragma unroll
            for (int k = 0; k < 8; k++) t[k] = o[k * 3 + c];
            st8(x1T + (long)c * N64 + (long)n * 64 + k8 * 8, t);
        }
    } else if (i < 294912) {
        long v = i - 262144; float o[8]; ld8(ey0, v, f, o); st8(c_ey0 + v * 8, o);
    } else if (i < 393216) {
        long v = i - 294912; float o[8]; ld8(ey1, v, f, o); st8(c_ey1 + v * 8, o);
    } else if (i < 655360) {
        long v = i - 393216; float o[8]; ld8(re, v, f, o); st8(c_re + v * 8, o);
    } else {
        long t = i - 655360;
        if (t < 4096)       { long r = t >> 6, c = t & 63;
                              c_Wup0[c * 64 + r] = f2us(ldf(Wup0, t, f)); }
        else if (t < 8192)  { t -= 4096; long r = t >> 6, c = t & 63;
                              c_Wup1[c * 64 + r] = f2us(ldf(Wup1, t, f)); }
        else if (t < 8704)  { t -= 8192; c_Rw1[t] = f2us(ldf(Rw1, t, f)); }
        else if (t < 25088) { t -= 8704; long r = t >> 8, c = t & 255;
                              c_Rw2[c * 64 + r] = f2us(ldf(Rw2, t, f)); }
        else if (t < 41472) { t -= 25088; long r = t >> 7, c = t & 127;
                              c_Wd0[c * 128 + r] = f2us(ldf(Wd0, t, f)); }
        else if (t < 49664) { t -= 41472; long r = t >> 6, c = t & 63;
                              c_Wd1[c * 128 + r] = f2us(ldf(Wd1, t, f)); }
        else if (t < 82432) { t -= 49664; long s = t >> 13, rm = t & 8191;
                              long r = rm >> 7, c = rm & 127;
                              c_Wsc0[s * 8192 + c * 64 + r] = f2us(ldf(Wsc0, t, f)); }
        else                { t -= 82432; long s = t >> 12, rm = t & 4095;
                              long r = rm >> 6, c = rm & 63;
                              c_Wsc1[s * 4096 + c * 64 + r] = f2us(ldf(Wsc1, t, f)); }
    }
}

// ---------------- CSR scan + scatter -------------------------------------------
__global__ void k_scan(const int* __restrict__ cnt, int* __restrict__ offs,
                       int* __restrict__ cursor) {
    __shared__ int sd[256];
    int t = threadIdx.x;
    int base = t * 64;
    const int4* c4 = (const int4*)cnt;
    int loc[64];
#pragma unroll
    for (int i = 0; i < 16; i++) {
        int4 v = c4[t * 16 + i];
        loc[i * 4 + 0] = v.x; loc[i * 4 + 1] = v.y; loc[i * 4 + 2] = v.z; loc[i * 4 + 3] = v.w;
    }
    int sum = 0;
#pragma unroll
    for (int i = 0; i < 64; i++) sum += loc[i];
    sd[t] = sum; __syncthreads();
    for (int off = 1; off < 256; off <<= 1) {
        int v = (t >= off) ? sd[t - off] : 0;
        __syncthreads();
        sd[t] += v;
        __syncthreads();
    }
    int run = sd[t] - sum;
    for (int i = 0; i < 64; i++) {
        offs[base + i] = run; cursor[base + i] = run;
        run += loc[i];
    }
    if (t == 255) offs[NN] = run;
}

// meta.w packs edge id (18 bits) | receiver node (14 bits) -------------------
__global__ void k_scatter(const int* __restrict__ recv, const int* __restrict__ senders,
                          const u16* __restrict__ ey0, const u16* __restrict__ ey1,
                          int* __restrict__ cursor, int4* __restrict__ meta) {
    int e = blockIdx.x * 256 + threadIdx.x;
    int node = recv[e];
    int p = atomicAdd(&cursor[node], 1);
    unsigned y0  = ey0[e];
    unsigned y1x = ey1[(long)e * 3 + 0];
    unsigned y1y = ey1[(long)e * 3 + 1];
    unsigned y1z = ey1[(long)e * 3 + 2];
    int4 m;
    m.x = senders[e];
    m.y = (int)(y0 | (y1x << 16));
    m.z = (int)(y1y | (y1z << 16));
    m.w = (int)((unsigned)e | ((unsigned)node << 18));
    meta[p] = m;
}

// ---------------- linear_up: h[node][64ch][4comp] interleaved bf16 --------------
__global__ void k_up_gemm(const u16* __restrict__ x0, const u16* __restrict__ x1T,
                          const u16* __restrict__ Wup0, const u16* __restrict__ Wup1,
                          u16* __restrict__ h) {
    int inst = blockIdx.y;
    int wv = threadIdx.x >> 6, lane = threadIdx.x & 63;
    int lhi = lane >> 4, llo = lane & 15;
    int mb = blockIdx.x * 256 + wv * 64;
    const u16* B = (inst == 0) ? Wup0 : Wup1;     // transposed [k_out=64][m=64]
    const u16* A = (inst == 0) ? x0 : (x1T + (long)(inst - 1) * N64);

    short8 bfr[4][2];
#pragma unroll
    for (int t = 0; t < 4; t++)
#pragma unroll
        for (int s = 0; s < 2; s++)
            bfr[t][s] = *reinterpret_cast<const short8*>(B + (long)(t * 16 + llo) * 64 + s * 32 + lhi * 8);

    f32x4 acc[4][4];
#pragma unroll
    for (int i = 0; i < 4; i++)
#pragma unroll
        for (int t = 0; t < 4; t++) acc[i][t] = 0.0f;

#pragma unroll
    for (int s = 0; s < 2; s++) {
        short8 af[4];
#pragma unroll
        for (int i = 0; i < 4; i++)
            af[i] = *reinterpret_cast<const short8*>(A + (long)(mb + i * 16 + llo) * 64 + s * 32 + lhi * 8);
#pragma unroll
        for (int i = 0; i < 4; i++)
#pragma unroll
            for (int t = 0; t < 4; t++)
                acc[i][t] = __builtin_amdgcn_mfma_f32_16x16x32_bf16(af[i], bfr[t][s], acc[i][t], 0, 0, 0);
    }
#pragma unroll
    for (int i = 0; i < 4; i++)
#pragma unroll
        for (int t = 0; t < 4; t++)
#pragma unroll
            for (int r = 0; r < 4; r++)
                h[(long)(mb + i * 16 + lhi * 4 + r) * 256 + (t * 16 + llo) * 4 + inst] =
                    f2us(acc[i][t][r] * 0.125f);
}

// ---------------- fused radial MLP + tensor-product gather (CSR-ordered) --------
// Round-6 verified configuration (k_edge 75 µs): RROW 268 (conflict-free phase-B
// stores: lhi bank offsets +0/+24/+16/+8), LDS 34304 B -> 4 blocks/CU,
// hid_s aliased into w_lds, phase-C gather prefetch depth 2.
#define RROW 268
__global__ void __launch_bounds__(256, 4)
k_edge(const u16* __restrict__ re, const u16* __restrict__ Rw1,
       const u16* __restrict__ Rw2, const int4* __restrict__ meta,
       const u16* __restrict__ h, float* __restrict__ abuf32) {
    __shared__ u16 w_lds[64 * RROW];          // 34304 B; hid aliased below
    u16 (*hid_s)[72] = reinterpret_cast<u16 (*)[72]>(w_lds);

    int tid = threadIdx.x;
    int wv = tid >> 6, lane = tid & 63, lhi = lane >> 4, llo = lane & 15;
    int p0 = blockIdx.x * 64;

    // ---- phase A: radial hidden layer for this block's 64 CSR slots ----------
    {
        int el = tid >> 2;
        int jb = (tid & 3) * 16;
        int e = ((const int*)meta)[(long)(p0 + el) * 4 + 3] & 0x3FFFF;
        short8 r8 = *reinterpret_cast<const short8*>(re + (long)e * 8);
        float rr[8];
#pragma unroll
        for (int r = 0; r < 8; r++) rr[r] = us2f((u16)r8[r]);
        float hv[16];
#pragma unroll
        for (int q = 0; q < 2; q++) {
            short8 w8 = *reinterpret_cast<const short8*>(Rw1 + jb + q * 8);
#pragma unroll
            for (int j = 0; j < 8; j++) hv[q * 8 + j] = rr[0] * us2f((u16)w8[j]);
        }
#pragma unroll
        for (int r = 1; r < 8; r++) {
#pragma unroll
            for (int q = 0; q < 2; q++) {
                short8 w8 = *reinterpret_cast<const short8*>(Rw1 + (long)r * 64 + jb + q * 8);
#pragma unroll
                for (int j = 0; j < 8; j++) hv[q * 8 + j] += rr[r] * us2f((u16)w8[j]);
            }
        }
#pragma unroll
        for (int q = 0; q < 4; q++) {
            ushort4 pk;
            pk.x = f2us(silu_f(hv[q * 4 + 0] * 0.35355339059327373f));
            pk.y = f2us(silu_f(hv[q * 4 + 1] * 0.35355339059327373f));
            pk.z = f2us(silu_f(hv[q * 4 + 2] * 0.35355339059327373f));
            pk.w = f2us(silu_f(hv[q * 4 + 3] * 0.35355339059327373f));
            *reinterpret_cast<ushort4*>(&hid_s[el][jb + q * 4]) = pk;
        }
    }
    __syncthreads();

    // ---- phase B: hid[64x64] @ Rw2T -> w_lds[64 slots][256] -------------------
    {
        short8 bfr[4][2];
#pragma unroll
        for (int t = 0; t < 4; t++)
#pragma unroll
            for (int s = 0; s < 2; s++)
                bfr[t][s] = *reinterpret_cast<const short8*>(
                    Rw2 + (long)(wv * 64 + t * 16 + llo) * 64 + s * 32 + lhi * 8);
        f32x4 acc[4][4];
#pragma unroll
        for (int i = 0; i < 4; i++)
#pragma unroll
            for (int t = 0; t < 4; t++) acc[i][t] = 0.0f;
#pragma unroll
        for (int s = 0; s < 2; s++) {
            short8 af[4];
#pragma unroll
            for (int i = 0; i < 4; i++)
                af[i] = *reinterpret_cast<const short8*>(&hid_s[i * 16 + llo][s * 32 + lhi * 8]);
#pragma unroll
            for (int i = 0; i < 4; i++)
#pragma unroll
                for (int t = 0; t < 4; t++)
                    acc[i][t] = __builtin_amdgcn_mfma_f32_16x16x32_bf16(af[i], bfr[t][s], acc[i][t], 0, 0, 0);
        }
        __syncthreads();     // all hid reads done; safe to overwrite region with w
#pragma unroll
        for (int i = 0; i < 4; i++)
#pragma unroll
            for (int t = 0; t < 4; t++)
#pragma unroll
                for (int r = 0; r < 4; r++)
                    w_lds[(i * 16 + lhi * 4 + r) * RROW + wv * 64 + t * 16 + llo] =
                        f2us(acc[i][t][r] * 0.125f);
    }
    __syncthreads();

    // ---- phase C: messages + segmented atomic reduction (prefetch depth 2) ----
    {
        const float qn = 0.25f;                 // 1/sqrt(avg_neigh)
        const float rs3 = 0.57735026918962576f; // 1/sqrt(3)
        int l = lane;
        int base = wv * 16;
        float acc[8];
#pragma unroll
        for (int r = 0; r < 8; r++) acc[r] = 0.f;
        int cur = -1;

        int4 ma = meta[p0 + base];
        ushort4 ha = *reinterpret_cast<const ushort4*>(h + (long)ma.x * 256 + l * 4);
        int4 mb_ = meta[p0 + base + 1];
        ushort4 hb = *reinterpret_cast<const ushort4*>(h + (long)mb_.x * 256 + l * 4);

        for (int ss = 0; ss < 16; ss++) {
            int4 mc = mb_; ushort4 hc = hb;
            if (ss + 2 < 16) {
                mc = meta[p0 + base + ss + 2];
                hc = *reinterpret_cast<const ushort4*>(h + (long)mc.x * 256 + l * 4);
            }
            int node = (int)(((unsigned)ma.w) >> 18);
            if (node != cur) {                       // wave-uniform branch
                if (cur >= 0) {
                    float* dst = abuf32 + (long)cur * 512 + l;
                    atomicAdd(dst,        acc[0] * qn);
                    atomicAdd(dst + 64,   acc[1] * qn * rs3);
                    atomicAdd(dst + 128,  acc[2] * qn);
                    atomicAdd(dst + 192,  acc[3] * qn);
                    atomicAdd(dst + 256,  acc[4] * qn);
                    atomicAdd(dst + 320,  acc[5] * qn);
                    atomicAdd(dst + 384,  acc[6] * qn);
                    atomicAdd(dst + 448,  acc[7] * qn);
                }
                cur = node;
#pragma unroll
                for (int r = 0; r < 8; r++) acc[r] = 0.f;
            }
            int sl = base + ss;
            float w0 = us2f(w_lds[sl * RROW + l]);
            float w1 = us2f(w_lds[sl * RROW + 64 + l]);
            float w2 = us2f(w_lds[sl * RROW + 128 + l]);
            float w3 = us2f(w_lds[sl * RROW + 192 + l]);
            float y0  = us2f((u16)((unsigned)ma.y & 0xffff));
            float y1x = us2f((u16)((unsigned)ma.y >> 16));
            float y1y = us2f((u16)((unsigned)ma.z & 0xffff));
            float y1z = us2f((u16)((unsigned)ma.z >> 16));
            float s0 = us2f(ha.x), s1x = us2f(ha.y), s1y = us2f(ha.z), s1z = us2f(ha.w);
            acc[0] += w0 * s0 * y0;
            acc[1] += w1 * (s1x * y1x + s1y * y1y + s1z * y1z);
            acc[2] += w2 * s0 * y1x;  acc[3] += w3 * s1x * y0;
            acc[4] += w2 * s0 * y1y;  acc[5] += w3 * s1y * y0;
            acc[6] += w2 * s0 * y1z;  acc[7] += w3 * s1z * y0;
            ma = mb_; ha = hb; mb_ = mc; hb = hc;
        }
        {
            float* dst = abuf32 + (long)cur * 512 + l;
            atomicAdd(dst,        acc[0] * qn);
            atomicAdd(dst + 64,   acc[1] * qn * rs3);
            atomicAdd(dst + 128,  acc[2] * qn);
            atomicAdd(dst + 192,  acc[3] * qn);
            atomicAdd(dst + 256,  acc[4] * qn);
            atomicAdd(dst + 320,  acc[5] * qn);
            atomicAdd(dst + 384,  acc[6] * qn);
            atomicAdd(dst + 448,  acc[7] * qn);
        }
    }
}

// ---------------- linear_down + species sc + gate (MFMA) ------------------------
// Block = 32 nodes, 5 waves: wave g = output group {scal, gate, vx, vy, vz}.
// A-operand for the down-GEMM comes from f32 abuf32 (converted to bf16 in-reg).
// Vector outputs staged in LDS and written as fully-coalesced float4.
#define DN 32
__global__ void __launch_bounds__(320, 3)
k_down(const float* __restrict__ abuf32, const u16* __restrict__ x0,
       const u16* __restrict__ x1T, const int* __restrict__ species,
       const u16* __restrict__ Wd0T, const u16* __restrict__ Wd1T,
       const u16* __restrict__ Wsc0T, const u16* __restrict__ Wsc1T,
       float* __restrict__ out) {
    __shared__ float gate_s[DN][65];
    __shared__ float vec_s[DN * 192];       // raw f1 in output order [row][col*3+c]
    __shared__ int sp_s[DN];
    int tid = threadIdx.x;
    int g = tid >> 6;
    int lane = tid & 63, lhi = lane >> 4, llo = lane & 15;
    int node0 = blockIdx.x * DN;
    if (tid < DN) sp_s[tid] = species[node0 + tid];
    __syncthreads();

    const float* Ad; const u16* BdT; int bcol;
    const u16* As; const u16* BsT; int sstr;
    if (g <= 1) { Ad = abuf32; BdT = Wd0T; bcol = g * 64; As = x0; BsT = Wsc0T; sstr = 8192; }
    else        { Ad = abuf32 + (g - 1) * 128; BdT = Wd1T; bcol = 0;
                  As = x1T + (long)(g - 2) * N64; BsT = Wsc1T; sstr = 4096; }

    const float inv2 = 0.08838834764831845f;  // 1/sqrt(128)
    const float inv  = 0.125f;                // 1/sqrt(64)

    // ---- self-connection phase: all species, row-select -----------------------
    short8 a2[DN / 16][2];
#pragma unroll
    for (int rt = 0; rt < DN / 16; rt++)
#pragma unroll
        for (int ks = 0; ks < 2; ks++)
            a2[rt][ks] = *reinterpret_cast<const short8*>(
                As + (long)(node0 + rt * 16 + llo) * 64 + ks * 32 + lhi * 8);

    f32x4 res[DN / 16][4];
#pragma unroll
    for (int rt = 0; rt < DN / 16; rt++)
#pragma unroll
        for (int ct = 0; ct < 4; ct++) res[rt][ct] = 0.0f;

    for (int s = 0; s < 4; s++) {
        short8 bs[4][2];
#pragma unroll
        for (int ct = 0; ct < 4; ct++)
#pragma unroll
            for (int ks = 0; ks < 2; ks++)
                bs[ct][ks] = *reinterpret_cast<const short8*>(
                    BsT + (long)s * sstr + (long)(bcol + ct * 16 + llo) * 64 + ks * 32 + lhi * 8);
#pragma unroll
        for (int rt = 0; rt < DN / 16; rt++) {
            f32x4 accs[4];
#pragma unroll
            for (int ct = 0; ct < 4; ct++) accs[ct] = 0.0f;
#pragma unroll
            for (int ks = 0; ks < 2; ks++)
#pragma unroll
                for (int ct = 0; ct < 4; ct++)
                    accs[ct] = __builtin_amdgcn_mfma_f32_16x16x32_bf16(a2[rt][ks], bs[ct][ks], accs[ct], 0, 0, 0);
#pragma unroll
            for (int r = 0; r < 4; r++) {
                int sp = sp_s[rt * 16 + lhi * 4 + r];
                if (sp == s)
#pragma unroll
                    for (int ct = 0; ct < 4; ct++) res[rt][ct][r] = accs[ct][r];
            }
        }
    }

    // ---- linear_down phase -----------------------------------------------------
    short8 bd[4][4];
#pragma unroll
    for (int ct = 0; ct < 4; ct++)
#pragma unroll
        for (int ks = 0; ks < 4; ks++)
            bd[ct][ks] = *reinterpret_cast<const short8*>(
                BdT + (long)(bcol + ct * 16 + llo) * 128 + ks * 32 + lhi * 8);

#pragma unroll
    for (int rt = 0; rt < DN / 16; rt++) {
        f32x4 accd[4];
#pragma unroll
        for (int ct = 0; ct < 4; ct++) accd[ct] = 0.0f;
#pragma unroll
        for (int ks = 0; ks < 4; ks++) {
            short8 a = f32x8_to_bf16(Ad + (long)(node0 + rt * 16 + llo) * 512 + ks * 32 + lhi * 8);
#pragma unroll
            for (int ct = 0; ct < 4; ct++)
                accd[ct] = __builtin_amdgcn_mfma_f32_16x16x32_bf16(a, bd[ct][ks], accd[ct], 0, 0, 0);
        }
#pragma unroll
        for (int ct = 0; ct < 4; ct++)
#pragma unroll
            for (int r = 0; r < 4; r++) {
                float fvv = 0.5f * (accd[ct][r] * inv2 + res[rt][ct][r] * inv);
                int row = rt * 16 + lhi * 4 + r;
                int col = ct * 16 + llo;
                if (g == 0) {
                    out[(long)(node0 + row) * 64 + col] = silu_f(fvv);
                } else if (g == 1) {
                    gate_s[row][col] = silu_f(fvv);
                } else {
                    vec_s[row * 192 + col * 3 + (g - 2)] = fvv;
                }
            }
    }
    __syncthreads();

    // ---- cooperative coalesced vector store (gate applied here) ---------------
    {
        float* vout = out + (long)N64 + (long)node0 * 192;
        for (int q4 = tid; q4 < DN * 48; q4 += 320) {
            int q = q4 * 4;
            int row = q4 / 48;                // 48 float4 per node row
            int rem = q - row * 192;
            f32x4 v = *reinterpret_cast<const f32x4*>(&vec_s[q]);
#pragma unroll
            for (int e = 0; e < 4; e++) v[e] *= gate_s[row][(rem + e) / 3];
            *reinterpret_cast<f32x4*>(vout + q) = v;
        }
    }
}

// ---------------- host launch --------------------------------------------------
extern "C" void kernel_launch(void* const* d_in, const int* in_sizes, int n_in,
                              void* d_out, int out_size, void* d_ws, size_t ws_size,
                              hipStream_t stream) {
    const int* senders   = (const int*)d_in[5];
    const int* receivers = (const int*)d_in[6];
    const int* species   = (const int*)d_in[7];
    float* out = (float*)d_out;

    char* ws = (char*)d_ws;
    size_t o = 0;
    auto alloc = [&](size_t bytes) { size_t p = o; o = (o + bytes + 255) & ~255UL; return p; };
    int* flag   = (int*)(ws + alloc(4));
    int* cnt    = (int*)(ws + alloc((size_t)NN * 4));
    int* offs   = (int*)(ws + alloc((size_t)(NN + 1) * 4));
    int* cursor = (int*)(ws + alloc((size_t)NN * 4));
    int4* meta  = (int4*)(ws + alloc((size_t)NE * 16));
    u16* c_x0   = (u16*)(ws + alloc(SB0 * 2));
    u16* x1T    = (u16*)(ws + alloc((size_t)3 * N64 * 2));
    u16* c_ey0  = (u16*)(ws + alloc((SB2 - SB1) * 2));
    u16* c_ey1  = (u16*)(ws + alloc((SB3 - SB2) * 2));
    u16* c_re   = (u16*)(ws + alloc((SB4 - SB3) * 2));
    u16* c_Wup0 = (u16*)(ws + alloc((SB5 - SB4) * 2));
    u16* c_Wup1 = (u16*)(ws + alloc((SB6 - SB5) * 2));
    u16* c_Rw1  = (u16*)(ws + alloc((SB7 - SB6) * 2));
    u16* c_Rw2  = (u16*)(ws + alloc((SB8 - SB7) * 2));
    u16* c_Wd0  = (u16*)(ws + alloc((SB9 - SB8) * 2));
    u16* c_Wd1  = (u16*)(ws + alloc((SB10 - SB9) * 2));
    u16* c_Wsc0 = (u16*)(ws + alloc((SB11 - SB10) * 2));
    u16* c_Wsc1 = (u16*)(ws + alloc((SB12 - SB11) * 2));
    u16* h      = (u16*)(ws + alloc((size_t)NN * 256 * 2));   // [node][64][4]
    float* abuf32 = (float*)(ws + alloc((size_t)NN * 512 * 4)); // [node][512] f32

    k_sniff<<<1, 64, 0, stream>>>((const u16*)d_in[4], flag);
    (void)hipMemsetAsync(cnt, 0, (size_t)NN * 4, stream);
    (void)hipMemsetAsync(abuf32, 0, (size_t)NN * 512 * 4, stream);
    k_convert<<<2946, 256, 0, stream>>>(d_in[0], d_in[1], d_in[2], d_in[3], d_in[4],
        d_in[8], d_in[9], d_in[10], d_in[11], d_in[12], d_in[13], d_in[14], d_in[15],
        flag, receivers, cnt,
        c_x0, x1T, c_ey0, c_ey1, c_re,
        c_Wup0, c_Wup1, c_Rw1, c_Rw2, c_Wd0, c_Wd1, c_Wsc0, c_Wsc1);
    k_scan<<<1, 256, 0, stream>>>(cnt, offs, cursor);
    k_scatter<<<NE / 256, 256, 0, stream>>>(receivers, senders, c_ey0, c_ey1,
                                            cursor, meta);

    k_up_gemm<<<dim3(NN / 256, 4), 256, 0, stream>>>(c_x0, x1T, c_Wup0, c_Wup1, h);

    k_edge<<<NE / 64, 256, 0, stream>>>(c_re, c_Rw1, c_Rw2, meta, h, abuf32);

    k_down<<<NN / DN, 320, 0, stream>>>(abuf32, c_x0, x1T, species,
                                        c_Wd0, c_Wd1, c_Wsc0, c_Wsc1, out);
}